// Round 12
// baseline (188.781 us; speedup 1.0000x reference)
//
#include <hip/hip_runtime.h>

typedef unsigned short u16;
typedef unsigned int u32;
typedef __attribute__((ext_vector_type(8))) short bf16x8;
typedef __attribute__((ext_vector_type(4))) float f32x4;

#define IN_F 128
#define CAP  8192   // record capacity per 256-node bucket (mean ~4.4K, +58 sigma)
#define EPB  8192   // edges per binA block

// ---------- helpers ----------
__device__ inline float bf2f(u16 v) {
    return __uint_as_float(((unsigned)v) << 16);
}
__device__ inline u16 f2bf(float f) {
    unsigned u = __float_as_uint(f);
    return (u16)((u + 0x7fffu + ((u >> 16) & 1u)) >> 16);
}

__device__ inline int block_scan_excl(int v, int* sdat) {
    int tid = threadIdx.x;
    sdat[tid] = v;
    __syncthreads();
#pragma unroll
    for (int off = 1; off < 256; off <<= 1) {
        int t = (tid >= off) ? sdat[tid - off] : 0;
        __syncthreads();
        sdat[tid] += t;
        __syncthreads();
    }
    return sdat[tid] - v;
}

// ---------------- degree + dis (global, before binning) ----------------

__global__ void k_init_cnt(int* cnt, int n) {
    int i = blockIdx.x * blockDim.x + threadIdx.x;
    if (i < n) cnt[i] = 1;  // self-loop
}

__global__ void k_count(const int* __restrict__ dst, int* cnt, int E) {
    int e = blockIdx.x * blockDim.x + threadIdx.x;
    if (e < E) atomicAdd(&cnt[dst[e]], 1);
}

__global__ void k_dis(const int* __restrict__ cnt, float* __restrict__ dis, int n) {
    int i = blockIdx.x * blockDim.x + threadIdx.x;
    if (i < n) dis[i] = rsqrtf((float)cnt[i]);
}

// ---------------- CSR construction (block-aggregated binning) ----------------

__global__ void k_zero(int* bcur, int nbuk) {
    for (int i = threadIdx.x; i < nbuk; i += 256) bcur[i] = 0;
}

// binA: block-aggregated scatter of {src16, dlocal8} into per-bucket regions.
__global__ __launch_bounds__(256) void k_binA(const int* __restrict__ ei,
                                              int* bcur, u32* __restrict__ tmp,
                                              int E, int n, int nbuk) {
    __shared__ int hist[256];
    const int tid = threadIdx.x;
    const int EN = E + n;
    const int t0 = blockIdx.x * EPB;
    const int t1 = min(t0 + EPB, EN);
    hist[tid] = 0;
    __syncthreads();
    for (int t = t0 + tid; t < t1; t += 256) {
        int d = (t < E) ? ei[E + t] : (t - E);
        atomicAdd(&hist[d >> 8], 1);
    }
    __syncthreads();
    if (tid < nbuk) {
        int r = hist[tid];
        int g = (r > 0) ? atomicAdd(&bcur[tid], r) : 0;
        hist[tid] = tid * CAP + g;
    }
    __syncthreads();
    for (int t = t0 + tid; t < t1; t += 256) {
        int s, d;
        if (t < E) { s = ei[t]; d = ei[E + t]; }
        else       { s = t - E; d = s; }
        int bk = d >> 8;
        int pos = atomicAdd(&hist[bk], 1);
        if (pos < (bk + 1) * CAP)
            tmp[pos] = (u32)s | ((u32)(d & 255) << 16);
    }
}

// scanb: exclusive scan over bucket totals -> bbase; row_ptr[n] = grand total
__global__ __launch_bounds__(256) void k_scanb(const int* __restrict__ bcur,
                                               int* __restrict__ bbase,
                                               int* __restrict__ row_ptr,
                                               int nbuk, int n) {
    __shared__ int sdat[256];
    __shared__ int carry;
    int tid = threadIdx.x;
    if (tid == 0) carry = 0;
    __syncthreads();
    for (int base = 0; base < nbuk; base += 256) {
        int i = base + tid;
        int v = (i < nbuk) ? min(bcur[i], CAP) : 0;
        int ex = block_scan_excl(v, sdat);
        if (i < nbuk) bbase[i] = carry + ex;
        int tot = sdat[255];
        __syncthreads();
        if (tid == 0) carry += tot;
        __syncthreads();
    }
    if (tid == 0) row_ptr[n] = carry;
}

// binB: one block per 256-node bucket. row_ptr from record counts; pack
// es32 records {src16 | bf16(dis[s]*dis[d])<<16} via LDS cursors.
__global__ __launch_bounds__(256) void k_binB(const u32* __restrict__ tmp,
                                              const int* __restrict__ bcur,
                                              const int* __restrict__ bbase,
                                              const float* __restrict__ dis,
                                              int* __restrict__ row_ptr,
                                              u32* __restrict__ es, int n) {
    __shared__ int cnt_l[256];
    __shared__ int sdat[256];
    __shared__ float ldis[256];
    __shared__ u32 es_lds[CAP];
    const int b = blockIdx.x;
    const int tid = threadIdx.x;
    const int total = min(bcur[b], CAP);
    const int gbase = bbase[b];
    const u32* rec0 = tmp + (size_t)b * CAP;
    int node = b * 256 + tid;
    cnt_l[tid] = 0;
    ldis[tid] = (node < n) ? dis[node] : 0.f;
    __syncthreads();
    for (int i = tid; i < total; i += 256)
        atomicAdd(&cnt_l[rec0[i] >> 16], 1);
    __syncthreads();
    int deg = cnt_l[tid];
    int ex = block_scan_excl(deg, sdat);
    if (node < n) row_ptr[node] = gbase + ex;
    __syncthreads();
    cnt_l[tid] = ex;
    __syncthreads();
    for (int i = tid; i < total; i += 256) {
        u32 rec = rec0[i];
        int dl = rec >> 16;
        int s  = rec & 0xffff;
        float nrm = dis[s] * ldis[dl];
        int p = atomicAdd(&cnt_l[dl], 1);
        es_lds[p] = (u32)s | ((u32)f2bf(nrm) << 16);
    }
    __syncthreads();
    for (int i = tid; i < total; i += 256)
        es[gbase + i] = es_lds[i];
}

// ------- W pre-pack into MFMA B-fragment order: Wp[((h*NCT+ct)*4+kt)*64 + l][r] -------

template<int M>
__global__ void k_packW(const float* __restrict__ W, u16* __restrict__ Wp) {
    constexpr int NCT = M / 16;
    int t = blockIdx.x * blockDim.x + threadIdx.x;
    int total = 2 * NCT * 4 * 64;
    if (t >= total) return;
    int l  = t & 63;
    int q  = t >> 6;
    int kt = q & 3;
    int q2 = q >> 2;
    int ct = q2 % NCT;
    int h  = q2 / NCT;
    int col   = 16 * ct + (l & 15);
    int krow0 = 32 * kt + 8 * (l >> 4);
    u16* outp = Wp + (size_t)t * 8;
#pragma unroll
    for (int r = 0; r < 8; ++r) {
        float w  = W[(size_t)(krow0 + r) * M + col];
        u16 hi   = f2bf(w);
        outp[r] = (h == 0) ? hi : f2bf(w - bf2f(hi));
    }
}

// ------- GEMM1: h1[n,128](bf16) = X[n,128](f32) @ W1, 3-term bf16 split --------------

__global__ __launch_bounds__(256) void k_gemm1(const float* __restrict__ X,
                                               const u16* __restrict__ Wp,
                                               u16* __restrict__ Y, int n) {
    constexpr int NCT = 8;
    constexpr int WPW = 2 * NCT * 4 * 64 * 8;
    __shared__ u16 wlds[WPW];
    for (int i = threadIdx.x; i < WPW / 8; i += 256)
        ((uint4*)wlds)[i] = ((const uint4*)Wp)[i];
    __syncthreads();
    const int wid = threadIdx.x >> 6;
    const int l   = threadIdx.x & 63;
    const int lr  = l & 15;
    const int lg  = l >> 4;
#pragma unroll
    for (int rt = 0; rt < 4; ++rt) {
        const int row0 = blockIdx.x * 256 + rt * 64 + wid * 16;
        const int arow = row0 + lr;
        const bool rowok = arow < n;
        const float* xr = X + (size_t)arow * 128;
        bf16x8 ahi[4], alo[4];
#pragma unroll
        for (int kt = 0; kt < 4; ++kt) {
            float v[8];
            if (rowok) {
                float4 p0 = *(const float4*)(xr + 32 * kt + 8 * lg);
                float4 p1 = *(const float4*)(xr + 32 * kt + 8 * lg + 4);
                v[0] = p0.x; v[1] = p0.y; v[2] = p0.z; v[3] = p0.w;
                v[4] = p1.x; v[5] = p1.y; v[6] = p1.z; v[7] = p1.w;
            } else {
#pragma unroll
                for (int r = 0; r < 8; ++r) v[r] = 0.f;
            }
#pragma unroll
            for (int r = 0; r < 8; ++r) {
                u16 hi = f2bf(v[r]);
                ahi[kt][r] = (short)hi;
                alo[kt][r] = (short)f2bf(v[r] - bf2f(hi));
            }
        }
#pragma unroll
        for (int ct = 0; ct < NCT; ++ct) {
            f32x4 acc = {0.f, 0.f, 0.f, 0.f};
            const u16* whi = wlds + (size_t)(ct * 4) * 512 + l * 8;
            const u16* wlo = whi + (size_t)NCT * 4 * 512;
#pragma unroll
            for (int kt = 0; kt < 4; ++kt) {
                bf16x8 bh = *(const bf16x8*)(whi + kt * 512);
                bf16x8 bl = *(const bf16x8*)(wlo + kt * 512);
                acc = __builtin_amdgcn_mfma_f32_16x16x32_bf16(ahi[kt], bh, acc, 0, 0, 0);
                acc = __builtin_amdgcn_mfma_f32_16x16x32_bf16(alo[kt], bh, acc, 0, 0, 0);
                acc = __builtin_amdgcn_mfma_f32_16x16x32_bf16(ahi[kt], bl, acc, 0, 0, 0);
            }
#pragma unroll
            for (int r = 0; r < 4; ++r) {
                int row = row0 + lg * 4 + r;
                if (row < n) Y[(size_t)row * 128 + 16 * ct + lr] = f2bf(acc[r]);
            }
        }
    }
}

// ------- GEMM2: h2[n,64](bf16) = a1[n,128](bf16) @ W2, 2-term (A exact bf16) --------

__global__ __launch_bounds__(256) void k_gemm2(const u16* __restrict__ A,
                                               const u16* __restrict__ Wp,
                                               u16* __restrict__ Y, int n) {
    constexpr int NCT = 4;
    constexpr int WPW = 2 * NCT * 4 * 64 * 8;
    __shared__ u16 wlds[WPW];
    for (int i = threadIdx.x; i < WPW / 8; i += 256)
        ((uint4*)wlds)[i] = ((const uint4*)Wp)[i];
    __syncthreads();
    const int wid = threadIdx.x >> 6;
    const int l   = threadIdx.x & 63;
    const int lr  = l & 15;
    const int lg  = l >> 4;
#pragma unroll
    for (int rt = 0; rt < 4; ++rt) {
        const int row0 = blockIdx.x * 256 + rt * 64 + wid * 16;
        const int arow = row0 + lr;
        const bool rowok = arow < n;
        bf16x8 a[4];
#pragma unroll
        for (int kt = 0; kt < 4; ++kt) {
            if (rowok) {
                a[kt] = *(const bf16x8*)(A + (size_t)arow * 128 + 32 * kt + 8 * lg);
            } else {
#pragma unroll
                for (int r = 0; r < 8; ++r) a[kt][r] = 0;
            }
        }
#pragma unroll
        for (int ct = 0; ct < NCT; ++ct) {
            f32x4 acc = {0.f, 0.f, 0.f, 0.f};
            const u16* whi = wlds + (size_t)(ct * 4) * 512 + l * 8;
            const u16* wlo = whi + (size_t)NCT * 4 * 512;
#pragma unroll
            for (int kt = 0; kt < 4; ++kt) {
                bf16x8 bh = *(const bf16x8*)(whi + kt * 512);
                bf16x8 bl = *(const bf16x8*)(wlo + kt * 512);
                acc = __builtin_amdgcn_mfma_f32_16x16x32_bf16(a[kt], bh, acc, 0, 0, 0);
                acc = __builtin_amdgcn_mfma_f32_16x16x32_bf16(a[kt], bl, acc, 0, 0, 0);
            }
#pragma unroll
            for (int r = 0; r < 4; ++r) {
                int row = row0 + lg * 4 + r;
                if (row < n) Y[(size_t)row * 64 + 16 * ct + lr] = f2bf(acc[r]);
            }
        }
    }
}

// ------- agg128: 2 half-wave edge streams x 4-unroll (8 edges in flight) -----------
// record r: src = r&0xffff, w = bf16(dis[s]*dis[d]) in high 16 bits.

__global__ __launch_bounds__(256) void k_agg128(const u16* __restrict__ h,
                                                const int* __restrict__ row_ptr,
                                                const u32* __restrict__ es,
                                                const float* __restrict__ bias,
                                                u16* __restrict__ out, int n) {
    int node = blockIdx.x * 4 + (threadIdx.x >> 6);
    if (node >= n) return;
    int lane = threadIdx.x & 63;
    int half = lane >> 5;
    int li   = lane & 31;      // cols 4li..4li+3
    int beg = row_ptr[node], end = row_ptr[node + 1];
    const u16* hp = h + li * 4;
    float a0 = 0.f, a1 = 0.f, a2 = 0.f, a3 = 0.f;
    float b0 = 0.f, b1 = 0.f, b2 = 0.f, b3 = 0.f;
    float c0 = 0.f, c1 = 0.f, c2 = 0.f, c3 = 0.f;
    float d0 = 0.f, d1 = 0.f, d2 = 0.f, d3 = 0.f;
    int e = beg + half;
    for (; e + 6 < end; e += 8) {
        u32 r0 = es[e], r1 = es[e + 2], r2 = es[e + 4], r3 = es[e + 6];
        ushort4 v0 = *(const ushort4*)(hp + (size_t)(r0 & 0xffff) * 128);
        ushort4 v1 = *(const ushort4*)(hp + (size_t)(r1 & 0xffff) * 128);
        ushort4 v2 = *(const ushort4*)(hp + (size_t)(r2 & 0xffff) * 128);
        ushort4 v3 = *(const ushort4*)(hp + (size_t)(r3 & 0xffff) * 128);
        float w0 = bf2f((u16)(r0 >> 16)), w1 = bf2f((u16)(r1 >> 16));
        float w2 = bf2f((u16)(r2 >> 16)), w3 = bf2f((u16)(r3 >> 16));
        a0 += w0 * bf2f(v0.x); a1 += w0 * bf2f(v0.y);
        a2 += w0 * bf2f(v0.z); a3 += w0 * bf2f(v0.w);
        b0 += w1 * bf2f(v1.x); b1 += w1 * bf2f(v1.y);
        b2 += w1 * bf2f(v1.z); b3 += w1 * bf2f(v1.w);
        c0 += w2 * bf2f(v2.x); c1 += w2 * bf2f(v2.y);
        c2 += w2 * bf2f(v2.z); c3 += w2 * bf2f(v2.w);
        d0 += w3 * bf2f(v3.x); d1 += w3 * bf2f(v3.y);
        d2 += w3 * bf2f(v3.z); d3 += w3 * bf2f(v3.w);
    }
    for (; e < end; e += 2) {
        u32 r0 = es[e];
        float w0 = bf2f((u16)(r0 >> 16));
        ushort4 v0 = *(const ushort4*)(hp + (size_t)(r0 & 0xffff) * 128);
        a0 += w0 * bf2f(v0.x); a1 += w0 * bf2f(v0.y);
        a2 += w0 * bf2f(v0.z); a3 += w0 * bf2f(v0.w);
    }
    a0 = (a0 + b0) + (c0 + d0);
    a1 = (a1 + b1) + (c1 + d1);
    a2 = (a2 + b2) + (c2 + d2);
    a3 = (a3 + b3) + (c3 + d3);
    a0 += __shfl_xor(a0, 32, 64);
    a1 += __shfl_xor(a1, 32, 64);
    a2 += __shfl_xor(a2, 32, 64);
    a3 += __shfl_xor(a3, 32, 64);
    if (half == 0) {
        float4 bv = *(const float4*)(bias + 4 * li);
        a0 = fmaxf(a0 + bv.x, 0.f);
        a1 = fmaxf(a1 + bv.y, 0.f);
        a2 = fmaxf(a2 + bv.z, 0.f);
        a3 = fmaxf(a3 + bv.w, 0.f);
        ushort4 o;
        o.x = f2bf(a0); o.y = f2bf(a1); o.z = f2bf(a2); o.w = f2bf(a3);
        *(ushort4*)(out + (size_t)node * 128 + 4 * li) = o;
    }
}

// ------- agg64: 4 quarter-wave edge streams x 4-unroll (16 edges in flight) --------

__global__ __launch_bounds__(256) void k_agg64(const u16* __restrict__ h,
                                               const int* __restrict__ row_ptr,
                                               const u32* __restrict__ es,
                                               const float* __restrict__ bias,
                                               float* __restrict__ out, int n) {
    int node = blockIdx.x * 4 + (threadIdx.x >> 6);
    if (node >= n) return;
    int lane = threadIdx.x & 63;
    int q  = lane >> 4;
    int li = lane & 15;        // cols 4li..4li+3
    int beg = row_ptr[node], end = row_ptr[node + 1];
    const u16* hp = h + li * 4;
    float a0 = 0.f, a1 = 0.f, a2 = 0.f, a3 = 0.f;
    float b0 = 0.f, b1 = 0.f, b2 = 0.f, b3 = 0.f;
    float c0 = 0.f, c1 = 0.f, c2 = 0.f, c3 = 0.f;
    float d0 = 0.f, d1 = 0.f, d2 = 0.f, d3 = 0.f;
    int e = beg + q;
    for (; e + 12 < end; e += 16) {
        u32 r0 = es[e], r1 = es[e + 4], r2 = es[e + 8], r3 = es[e + 12];
        ushort4 v0 = *(const ushort4*)(hp + (size_t)(r0 & 0xffff) * 64);
        ushort4 v1 = *(const ushort4*)(hp + (size_t)(r1 & 0xffff) * 64);
        ushort4 v2 = *(const ushort4*)(hp + (size_t)(r2 & 0xffff) * 64);
        ushort4 v3 = *(const ushort4*)(hp + (size_t)(r3 & 0xffff) * 64);
        float w0 = bf2f((u16)(r0 >> 16)), w1 = bf2f((u16)(r1 >> 16));
        float w2 = bf2f((u16)(r2 >> 16)), w3 = bf2f((u16)(r3 >> 16));
        a0 += w0 * bf2f(v0.x); a1 += w0 * bf2f(v0.y);
        a2 += w0 * bf2f(v0.z); a3 += w0 * bf2f(v0.w);
        b0 += w1 * bf2f(v1.x); b1 += w1 * bf2f(v1.y);
        b2 += w1 * bf2f(v1.z); b3 += w1 * bf2f(v1.w);
        c0 += w2 * bf2f(v2.x); c1 += w2 * bf2f(v2.y);
        c2 += w2 * bf2f(v2.z); c3 += w2 * bf2f(v2.w);
        d0 += w3 * bf2f(v3.x); d1 += w3 * bf2f(v3.y);
        d2 += w3 * bf2f(v3.z); d3 += w3 * bf2f(v3.w);
    }
    for (; e < end; e += 4) {
        u32 r0 = es[e];
        float w0 = bf2f((u16)(r0 >> 16));
        ushort4 v0 = *(const ushort4*)(hp + (size_t)(r0 & 0xffff) * 64);
        a0 += w0 * bf2f(v0.x); a1 += w0 * bf2f(v0.y);
        a2 += w0 * bf2f(v0.z); a3 += w0 * bf2f(v0.w);
    }
    a0 = (a0 + b0) + (c0 + d0);
    a1 = (a1 + b1) + (c1 + d1);
    a2 = (a2 + b2) + (c2 + d2);
    a3 = (a3 + b3) + (c3 + d3);
    a0 += __shfl_xor(a0, 16, 64); a0 += __shfl_xor(a0, 32, 64);
    a1 += __shfl_xor(a1, 16, 64); a1 += __shfl_xor(a1, 32, 64);
    a2 += __shfl_xor(a2, 16, 64); a2 += __shfl_xor(a2, 32, 64);
    a3 += __shfl_xor(a3, 16, 64); a3 += __shfl_xor(a3, 32, 64);
    if (q == 0) {
        float4 bv = *(const float4*)(bias + 4 * li);
        float4 o;
        o.x = a0 + bv.x; o.y = a1 + bv.y; o.z = a2 + bv.z; o.w = a3 + bv.w;
        *(float4*)(out + (size_t)node * 64 + 4 * li) = o;
    }
}

// ---------------- launch ----------------

static inline char* alignp(char* p, size_t a) {
    return (char*)(((uintptr_t)p + a - 1) & ~(uintptr_t)(a - 1));
}

extern "C" void kernel_launch(void* const* d_in, const int* in_sizes, int n_in,
                              void* d_out, int out_size, void* d_ws, size_t ws_size,
                              hipStream_t stream) {
    const float* x  = (const float*)d_in[0];
    const int*   ei = (const int*)d_in[1];
    const float* W1 = (const float*)d_in[2];
    const float* b1 = (const float*)d_in[3];
    const float* W2 = (const float*)d_in[4];
    const float* b2 = (const float*)d_in[5];
    float* out = (float*)d_out;

    const int n    = in_sizes[0] / IN_F;
    const int E    = in_sizes[1] / 2;
    const int EN   = E + n;
    const int nb   = (n + 255) / 256;
    const int NBUK = (n + 255) / 256;
    const int GB   = (n + 255) / 256;

    char* w = (char*)d_ws;
    int*   cnt      = (int*)w;   w = alignp(w + (size_t)n * 4, 256);
    int*   row_ptr  = (int*)w;   w = alignp(w + (size_t)(n + 1) * 4, 256);
    int*   bcur     = (int*)w;   w = alignp(w + (size_t)NBUK * 4, 256);
    int*   bbase    = (int*)w;   w = alignp(w + (size_t)NBUK * 4, 256);
    float* dis      = (float*)w; w = alignp(w + (size_t)n * 4, 256);
    u32*   tmp      = (u32*)w;   w = alignp(w + (size_t)NBUK * CAP * 4, 256);
    u32*   es       = (u32*)w;   w = alignp(w + (size_t)EN * 4, 256);
    u16*   w1p      = (u16*)w;   w = alignp(w + (size_t)2 * 8 * 4 * 64 * 8 * 2, 256);
    u16*   w2p      = (u16*)w;   w = alignp(w + (size_t)2 * 4 * 4 * 64 * 8 * 2, 256);
    u16*   h1b      = (u16*)w;   w = alignp(w + (size_t)n * 128 * 2, 256);
    u16*   a1b      = (u16*)w;   w = alignp(w + (size_t)n * 128 * 2, 256);
    u16*   h2b      = h1b;  // reuse: h1b dead after first aggregation

    k_init_cnt<<<nb, 256, 0, stream>>>(cnt, n);
    k_count<<<(E + 255) / 256, 256, 0, stream>>>(ei + E, cnt, E);
    k_dis<<<nb, 256, 0, stream>>>(cnt, dis, n);
    k_zero<<<1, 256, 0, stream>>>(bcur, NBUK);
    k_binA<<<(EN + EPB - 1) / EPB, 256, 0, stream>>>(ei, bcur, tmp, E, n, NBUK);
    k_scanb<<<1, 256, 0, stream>>>(bcur, bbase, row_ptr, NBUK, n);
    k_binB<<<NBUK, 256, 0, stream>>>(tmp, bcur, bbase, dis, row_ptr, es, n);
    k_packW<128><<<(2 * 8 * 4 * 64 + 255) / 256, 256, 0, stream>>>(W1, w1p);
    k_packW<64><<<(2 * 4 * 4 * 64 + 255) / 256, 256, 0, stream>>>(W2, w2p);

    k_gemm1<<<GB, 256, 0, stream>>>(x, w1p, h1b, n);
    k_agg128<<<(n + 3) / 4, 256, 0, stream>>>(h1b, row_ptr, es, b1, a1b, n);
    k_gemm2<<<GB, 256, 0, stream>>>(a1b, w2p, h2b, n);
    k_agg64<<<(n + 3) / 4, 256, 0, stream>>>(h2b, row_ptr, es, b2, out, n);
}

// Round 14
// 155.137 us; speedup vs baseline: 1.2169x; 1.2169x over previous
//
#include <hip/hip_runtime.h>

typedef unsigned short u16;
typedef unsigned int u32;
typedef __attribute__((ext_vector_type(8))) short bf16x8;
typedef __attribute__((ext_vector_type(4))) float f32x4;

#define IN_F 128
#define CAP  8192   // record capacity per 256-node bucket (mean ~4.4K, +58 sigma)
#define EPB  8192   // edges per binA block

// ---------- helpers ----------
__device__ inline float bf2f(u16 v) {
    return __uint_as_float(((unsigned)v) << 16);
}
__device__ inline u16 f2bf(float f) {
    unsigned u = __float_as_uint(f);
    return (u16)((u + 0x7fffu + ((u >> 16) & 1u)) >> 16);
}

__device__ inline int block_scan_excl(int v, int* sdat) {
    int tid = threadIdx.x;
    sdat[tid] = v;
    __syncthreads();
#pragma unroll
    for (int off = 1; off < 256; off <<= 1) {
        int t = (tid >= off) ? sdat[tid - off] : 0;
        __syncthreads();
        sdat[tid] += t;
        __syncthreads();
    }
    return sdat[tid] - v;
}

// ---------------- CSR construction (block-aggregated binning) ----------------

__global__ void k_zero(int* bcur, int nbuk) {
    for (int i = threadIdx.x; i < nbuk; i += 256) bcur[i] = 0;
}

// binA: block-aggregated scatter of {src16, dlocal8<<16} into per-bucket regions.
// Per-edge atomics are LDS-only; global atomics: one per (block,bucket).
__global__ __launch_bounds__(256) void k_binA(const int* __restrict__ ei,
                                              int* bcur, u32* __restrict__ tmp,
                                              int E, int n, int nbuk) {
    __shared__ int hist[256];
    const int tid = threadIdx.x;
    const int EN = E + n;
    const int t0 = blockIdx.x * EPB;
    const int t1 = min(t0 + EPB, EN);
    hist[tid] = 0;
    __syncthreads();
    for (int t = t0 + tid; t < t1; t += 256) {
        int d = (t < E) ? ei[E + t] : (t - E);
        atomicAdd(&hist[d >> 8], 1);
    }
    __syncthreads();
    if (tid < nbuk) {
        int r = hist[tid];
        int g = (r > 0) ? atomicAdd(&bcur[tid], r) : 0;
        hist[tid] = tid * CAP + g;
    }
    __syncthreads();
    for (int t = t0 + tid; t < t1; t += 256) {
        int s, d;
        if (t < E) { s = ei[t]; d = ei[E + t]; }
        else       { s = t - E; d = s; }
        int bk = d >> 8;
        int pos = atomicAdd(&hist[bk], 1);
        if (pos < (bk + 1) * CAP)
            tmp[pos] = (u32)s | ((u32)(d & 255) << 16);
    }
}

// scanb: exclusive scan over bucket totals -> bbase; row_ptr[n] = grand total
__global__ __launch_bounds__(256) void k_scanb(const int* __restrict__ bcur,
                                               int* __restrict__ bbase,
                                               int* __restrict__ row_ptr,
                                               int nbuk, int n) {
    __shared__ int sdat[256];
    __shared__ int carry;
    int tid = threadIdx.x;
    if (tid == 0) carry = 0;
    __syncthreads();
    for (int base = 0; base < nbuk; base += 256) {
        int i = base + tid;
        int v = (i < nbuk) ? min(bcur[i], CAP) : 0;
        int ex = block_scan_excl(v, sdat);
        if (i < nbuk) bbase[i] = carry + ex;
        int tot = sdat[255];
        __syncthreads();
        if (tid == 0) carry += tot;
        __syncthreads();
    }
    if (tid == 0) row_ptr[n] = carry;
}

// binB1: per bucket — LDS degree count + scan -> row_ptr, dis. No global atomics.
__global__ __launch_bounds__(256) void k_binB1(const u32* __restrict__ tmp,
                                               const int* __restrict__ bcur,
                                               const int* __restrict__ bbase,
                                               int* __restrict__ row_ptr,
                                               float* __restrict__ dis, int n) {
    __shared__ int cnt_l[256];
    __shared__ int sdat[256];
    const int b = blockIdx.x;
    const int tid = threadIdx.x;
    const int total = min(bcur[b], CAP);
    const u32* rec0 = tmp + (size_t)b * CAP;
    cnt_l[tid] = 0;
    __syncthreads();
    for (int i = tid; i < total; i += 256)
        atomicAdd(&cnt_l[rec0[i] >> 16], 1);
    __syncthreads();
    int deg = cnt_l[tid];
    int ex = block_scan_excl(deg, sdat);
    int node = b * 256 + tid;
    if (node < n) {
        row_ptr[node] = bbase[b] + ex;
        dis[node] = rsqrtf((float)deg);
    }
}

// binB2: per bucket — recount/rescan (LDS), then place es32 records
// {src16 | bf16(dis[src]*dis[dst])<<16} via LDS cursors; sequential copy out.
// dis[] is complete (binB1 ran as a prior dispatch).
__global__ __launch_bounds__(256) void k_binB2(const u32* __restrict__ tmp,
                                               const int* __restrict__ bcur,
                                               const int* __restrict__ bbase,
                                               const float* __restrict__ dis,
                                               u32* __restrict__ es, int n) {
    __shared__ int cnt_l[256];
    __shared__ int sdat[256];
    __shared__ float ldis[256];
    __shared__ u32 es_lds[CAP];
    const int b = blockIdx.x;
    const int tid = threadIdx.x;
    const int total = min(bcur[b], CAP);
    const int gbase = bbase[b];
    const u32* rec0 = tmp + (size_t)b * CAP;
    int node = b * 256 + tid;
    cnt_l[tid] = 0;
    ldis[tid] = (node < n) ? dis[node] : 0.f;
    __syncthreads();
    for (int i = tid; i < total; i += 256)
        atomicAdd(&cnt_l[rec0[i] >> 16], 1);
    __syncthreads();
    int deg = cnt_l[tid];
    int ex = block_scan_excl(deg, sdat);
    cnt_l[tid] = ex;   // safe: all cnt_l reads happened before scan's final barrier
    __syncthreads();
    for (int i = tid; i < total; i += 256) {
        u32 rec = rec0[i];
        int dl = rec >> 16;
        int s  = rec & 0xffff;
        float nrm = dis[s] * ldis[dl];
        int p = atomicAdd(&cnt_l[dl], 1);
        es_lds[p] = (u32)s | ((u32)f2bf(nrm) << 16);
    }
    __syncthreads();
    for (int i = tid; i < total; i += 256)
        es[gbase + i] = es_lds[i];
}

// ------- W pre-pack into MFMA B-fragment order: Wp[((h*NCT+ct)*4+kt)*64 + l][r] -------

template<int M>
__global__ void k_packW(const float* __restrict__ W, u16* __restrict__ Wp) {
    constexpr int NCT = M / 16;
    int t = blockIdx.x * blockDim.x + threadIdx.x;
    int total = 2 * NCT * 4 * 64;
    if (t >= total) return;
    int l  = t & 63;
    int q  = t >> 6;
    int kt = q & 3;
    int q2 = q >> 2;
    int ct = q2 % NCT;
    int h  = q2 / NCT;
    int col   = 16 * ct + (l & 15);
    int krow0 = 32 * kt + 8 * (l >> 4);
    u16* outp = Wp + (size_t)t * 8;
#pragma unroll
    for (int r = 0; r < 8; ++r) {
        float w  = W[(size_t)(krow0 + r) * M + col];
        u16 hi   = f2bf(w);
        outp[r] = (h == 0) ? hi : f2bf(w - bf2f(hi));
    }
}

// ------- GEMM1: h1[n,128](bf16) = X[n,128](f32) @ W1, 3-term bf16 split --------------

__global__ __launch_bounds__(256) void k_gemm1(const float* __restrict__ X,
                                               const u16* __restrict__ Wp,
                                               u16* __restrict__ Y, int n) {
    constexpr int NCT = 8;
    constexpr int WPW = 2 * NCT * 4 * 64 * 8;
    __shared__ u16 wlds[WPW];
    for (int i = threadIdx.x; i < WPW / 8; i += 256)
        ((uint4*)wlds)[i] = ((const uint4*)Wp)[i];
    __syncthreads();
    const int wid = threadIdx.x >> 6;
    const int l   = threadIdx.x & 63;
    const int lr  = l & 15;
    const int lg  = l >> 4;
#pragma unroll
    for (int rt = 0; rt < 4; ++rt) {
        const int row0 = blockIdx.x * 256 + rt * 64 + wid * 16;
        const int arow = row0 + lr;
        const bool rowok = arow < n;
        const float* xr = X + (size_t)arow * 128;
        bf16x8 ahi[4], alo[4];
#pragma unroll
        for (int kt = 0; kt < 4; ++kt) {
            float v[8];
            if (rowok) {
                float4 p0 = *(const float4*)(xr + 32 * kt + 8 * lg);
                float4 p1 = *(const float4*)(xr + 32 * kt + 8 * lg + 4);
                v[0] = p0.x; v[1] = p0.y; v[2] = p0.z; v[3] = p0.w;
                v[4] = p1.x; v[5] = p1.y; v[6] = p1.z; v[7] = p1.w;
            } else {
#pragma unroll
                for (int r = 0; r < 8; ++r) v[r] = 0.f;
            }
#pragma unroll
            for (int r = 0; r < 8; ++r) {
                u16 hi = f2bf(v[r]);
                ahi[kt][r] = (short)hi;
                alo[kt][r] = (short)f2bf(v[r] - bf2f(hi));
            }
        }
#pragma unroll
        for (int ct = 0; ct < NCT; ++ct) {
            f32x4 acc = {0.f, 0.f, 0.f, 0.f};
            const u16* whi = wlds + (size_t)(ct * 4) * 512 + l * 8;
            const u16* wlo = whi + (size_t)NCT * 4 * 512;
#pragma unroll
            for (int kt = 0; kt < 4; ++kt) {
                bf16x8 bh = *(const bf16x8*)(whi + kt * 512);
                bf16x8 bl = *(const bf16x8*)(wlo + kt * 512);
                acc = __builtin_amdgcn_mfma_f32_16x16x32_bf16(ahi[kt], bh, acc, 0, 0, 0);
                acc = __builtin_amdgcn_mfma_f32_16x16x32_bf16(alo[kt], bh, acc, 0, 0, 0);
                acc = __builtin_amdgcn_mfma_f32_16x16x32_bf16(ahi[kt], bl, acc, 0, 0, 0);
            }
#pragma unroll
            for (int r = 0; r < 4; ++r) {
                int row = row0 + lg * 4 + r;
                if (row < n) Y[(size_t)row * 128 + 16 * ct + lr] = f2bf(acc[r]);
            }
        }
    }
}

// ------- GEMM2: h2[n,64](bf16) = a1[n,128](bf16) @ W2, 2-term (A exact bf16) --------

__global__ __launch_bounds__(256) void k_gemm2(const u16* __restrict__ A,
                                               const u16* __restrict__ Wp,
                                               u16* __restrict__ Y, int n) {
    constexpr int NCT = 4;
    constexpr int WPW = 2 * NCT * 4 * 64 * 8;
    __shared__ u16 wlds[WPW];
    for (int i = threadIdx.x; i < WPW / 8; i += 256)
        ((uint4*)wlds)[i] = ((const uint4*)Wp)[i];
    __syncthreads();
    const int wid = threadIdx.x >> 6;
    const int l   = threadIdx.x & 63;
    const int lr  = l & 15;
    const int lg  = l >> 4;
#pragma unroll
    for (int rt = 0; rt < 4; ++rt) {
        const int row0 = blockIdx.x * 256 + rt * 64 + wid * 16;
        const int arow = row0 + lr;
        const bool rowok = arow < n;
        bf16x8 a[4];
#pragma unroll
        for (int kt = 0; kt < 4; ++kt) {
            if (rowok) {
                a[kt] = *(const bf16x8*)(A + (size_t)arow * 128 + 32 * kt + 8 * lg);
            } else {
#pragma unroll
                for (int r = 0; r < 8; ++r) a[kt][r] = 0;
            }
        }
#pragma unroll
        for (int ct = 0; ct < NCT; ++ct) {
            f32x4 acc = {0.f, 0.f, 0.f, 0.f};
            const u16* whi = wlds + (size_t)(ct * 4) * 512 + l * 8;
            const u16* wlo = whi + (size_t)NCT * 4 * 512;
#pragma unroll
            for (int kt = 0; kt < 4; ++kt) {
                bf16x8 bh = *(const bf16x8*)(whi + kt * 512);
                bf16x8 bl = *(const bf16x8*)(wlo + kt * 512);
                acc = __builtin_amdgcn_mfma_f32_16x16x32_bf16(a[kt], bh, acc, 0, 0, 0);
                acc = __builtin_amdgcn_mfma_f32_16x16x32_bf16(a[kt], bl, acc, 0, 0, 0);
            }
#pragma unroll
            for (int r = 0; r < 4; ++r) {
                int row = row0 + lg * 4 + r;
                if (row < n) Y[(size_t)row * 64 + 16 * ct + lr] = f2bf(acc[r]);
            }
        }
    }
}

// ------- agg128: 2 half-wave edge streams x 4-unroll (8 edges in flight) -----------
// record r: src = r&0xffff, w = bf16(dis[s]*dis[d]) in high 16 bits.

__global__ __launch_bounds__(256) void k_agg128(const u16* __restrict__ h,
                                                const int* __restrict__ row_ptr,
                                                const u32* __restrict__ es,
                                                const float* __restrict__ bias,
                                                u16* __restrict__ out, int n) {
    int node = blockIdx.x * 4 + (threadIdx.x >> 6);
    if (node >= n) return;
    int lane = threadIdx.x & 63;
    int half = lane >> 5;
    int li   = lane & 31;      // cols 4li..4li+3
    int beg = row_ptr[node], end = row_ptr[node + 1];
    const u16* hp = h + li * 4;
    float a0 = 0.f, a1 = 0.f, a2 = 0.f, a3 = 0.f;
    float b0 = 0.f, b1 = 0.f, b2 = 0.f, b3 = 0.f;
    float c0 = 0.f, c1 = 0.f, c2 = 0.f, c3 = 0.f;
    float d0 = 0.f, d1 = 0.f, d2 = 0.f, d3 = 0.f;
    int e = beg + half;
    for (; e + 6 < end; e += 8) {
        u32 r0 = es[e], r1 = es[e + 2], r2 = es[e + 4], r3 = es[e + 6];
        ushort4 v0 = *(const ushort4*)(hp + (size_t)(r0 & 0xffff) * 128);
        ushort4 v1 = *(const ushort4*)(hp + (size_t)(r1 & 0xffff) * 128);
        ushort4 v2 = *(const ushort4*)(hp + (size_t)(r2 & 0xffff) * 128);
        ushort4 v3 = *(const ushort4*)(hp + (size_t)(r3 & 0xffff) * 128);
        float w0 = bf2f((u16)(r0 >> 16)), w1 = bf2f((u16)(r1 >> 16));
        float w2 = bf2f((u16)(r2 >> 16)), w3 = bf2f((u16)(r3 >> 16));
        a0 += w0 * bf2f(v0.x); a1 += w0 * bf2f(v0.y);
        a2 += w0 * bf2f(v0.z); a3 += w0 * bf2f(v0.w);
        b0 += w1 * bf2f(v1.x); b1 += w1 * bf2f(v1.y);
        b2 += w1 * bf2f(v1.z); b3 += w1 * bf2f(v1.w);
        c0 += w2 * bf2f(v2.x); c1 += w2 * bf2f(v2.y);
        c2 += w2 * bf2f(v2.z); c3 += w2 * bf2f(v2.w);
        d0 += w3 * bf2f(v3.x); d1 += w3 * bf2f(v3.y);
        d2 += w3 * bf2f(v3.z); d3 += w3 * bf2f(v3.w);
    }
    for (; e < end; e += 2) {
        u32 r0 = es[e];
        float w0 = bf2f((u16)(r0 >> 16));
        ushort4 v0 = *(const ushort4*)(hp + (size_t)(r0 & 0xffff) * 128);
        a0 += w0 * bf2f(v0.x); a1 += w0 * bf2f(v0.y);
        a2 += w0 * bf2f(v0.z); a3 += w0 * bf2f(v0.w);
    }
    a0 = (a0 + b0) + (c0 + d0);
    a1 = (a1 + b1) + (c1 + d1);
    a2 = (a2 + b2) + (c2 + d2);
    a3 = (a3 + b3) + (c3 + d3);
    a0 += __shfl_xor(a0, 32, 64);
    a1 += __shfl_xor(a1, 32, 64);
    a2 += __shfl_xor(a2, 32, 64);
    a3 += __shfl_xor(a3, 32, 64);
    if (half == 0) {
        float4 bv = *(const float4*)(bias + 4 * li);
        a0 = fmaxf(a0 + bv.x, 0.f);
        a1 = fmaxf(a1 + bv.y, 0.f);
        a2 = fmaxf(a2 + bv.z, 0.f);
        a3 = fmaxf(a3 + bv.w, 0.f);
        ushort4 o;
        o.x = f2bf(a0); o.y = f2bf(a1); o.z = f2bf(a2); o.w = f2bf(a3);
        *(ushort4*)(out + (size_t)node * 128 + 4 * li) = o;
    }
}

// ------- agg64: 4 quarter-wave edge streams x 4-unroll (16 edges in flight) --------

__global__ __launch_bounds__(256) void k_agg64(const u16* __restrict__ h,
                                               const int* __restrict__ row_ptr,
                                               const u32* __restrict__ es,
                                               const float* __restrict__ bias,
                                               float* __restrict__ out, int n) {
    int node = blockIdx.x * 4 + (threadIdx.x >> 6);
    if (node >= n) return;
    int lane = threadIdx.x & 63;
    int q  = lane >> 4;
    int li = lane & 15;        // cols 4li..4li+3
    int beg = row_ptr[node], end = row_ptr[node + 1];
    const u16* hp = h + li * 4;
    float a0 = 0.f, a1 = 0.f, a2 = 0.f, a3 = 0.f;
    float b0 = 0.f, b1 = 0.f, b2 = 0.f, b3 = 0.f;
    float c0 = 0.f, c1 = 0.f, c2 = 0.f, c3 = 0.f;
    float d0 = 0.f, d1 = 0.f, d2 = 0.f, d3 = 0.f;
    int e = beg + q;
    for (; e + 12 < end; e += 16) {
        u32 r0 = es[e], r1 = es[e + 4], r2 = es[e + 8], r3 = es[e + 12];
        ushort4 v0 = *(const ushort4*)(hp + (size_t)(r0 & 0xffff) * 64);
        ushort4 v1 = *(const ushort4*)(hp + (size_t)(r1 & 0xffff) * 64);
        ushort4 v2 = *(const ushort4*)(hp + (size_t)(r2 & 0xffff) * 64);
        ushort4 v3 = *(const ushort4*)(hp + (size_t)(r3 & 0xffff) * 64);
        float w0 = bf2f((u16)(r0 >> 16)), w1 = bf2f((u16)(r1 >> 16));
        float w2 = bf2f((u16)(r2 >> 16)), w3 = bf2f((u16)(r3 >> 16));
        a0 += w0 * bf2f(v0.x); a1 += w0 * bf2f(v0.y);
        a2 += w0 * bf2f(v0.z); a3 += w0 * bf2f(v0.w);
        b0 += w1 * bf2f(v1.x); b1 += w1 * bf2f(v1.y);
        b2 += w1 * bf2f(v1.z); b3 += w1 * bf2f(v1.w);
        c0 += w2 * bf2f(v2.x); c1 += w2 * bf2f(v2.y);
        c2 += w2 * bf2f(v2.z); c3 += w2 * bf2f(v2.w);
        d0 += w3 * bf2f(v3.x); d1 += w3 * bf2f(v3.y);
        d2 += w3 * bf2f(v3.z); d3 += w3 * bf2f(v3.w);
    }
    for (; e < end; e += 4) {
        u32 r0 = es[e];
        float w0 = bf2f((u16)(r0 >> 16));
        ushort4 v0 = *(const ushort4*)(hp + (size_t)(r0 & 0xffff) * 64);
        a0 += w0 * bf2f(v0.x); a1 += w0 * bf2f(v0.y);
        a2 += w0 * bf2f(v0.z); a3 += w0 * bf2f(v0.w);
    }
    a0 = (a0 + b0) + (c0 + d0);
    a1 = (a1 + b1) + (c1 + d1);
    a2 = (a2 + b2) + (c2 + d2);
    a3 = (a3 + b3) + (c3 + d3);
    a0 += __shfl_xor(a0, 16, 64); a0 += __shfl_xor(a0, 32, 64);
    a1 += __shfl_xor(a1, 16, 64); a1 += __shfl_xor(a1, 32, 64);
    a2 += __shfl_xor(a2, 16, 64); a2 += __shfl_xor(a2, 32, 64);
    a3 += __shfl_xor(a3, 16, 64); a3 += __shfl_xor(a3, 32, 64);
    if (q == 0) {
        float4 bv = *(const float4*)(bias + 4 * li);
        float4 o;
        o.x = a0 + bv.x; o.y = a1 + bv.y; o.z = a2 + bv.z; o.w = a3 + bv.w;
        *(float4*)(out + (size_t)node * 64 + 4 * li) = o;
    }
}

// ---------------- launch ----------------

static inline char* alignp(char* p, size_t a) {
    return (char*)(((uintptr_t)p + a - 1) & ~(uintptr_t)(a - 1));
}

extern "C" void kernel_launch(void* const* d_in, const int* in_sizes, int n_in,
                              void* d_out, int out_size, void* d_ws, size_t ws_size,
                              hipStream_t stream) {
    const float* x  = (const float*)d_in[0];
    const int*   ei = (const int*)d_in[1];
    const float* W1 = (const float*)d_in[2];
    const float* b1 = (const float*)d_in[3];
    const float* W2 = (const float*)d_in[4];
    const float* b2 = (const float*)d_in[5];
    float* out = (float*)d_out;

    const int n    = in_sizes[0] / IN_F;
    const int E    = in_sizes[1] / 2;
    const int EN   = E + n;
    const int NBUK = (n + 255) / 256;
    const int GB   = (n + 255) / 256;

    char* w = (char*)d_ws;
    int*   row_ptr  = (int*)w;   w = alignp(w + (size_t)(n + 1) * 4, 256);
    int*   bcur     = (int*)w;   w = alignp(w + (size_t)NBUK * 4, 256);
    int*   bbase    = (int*)w;   w = alignp(w + (size_t)NBUK * 4, 256);
    float* dis      = (float*)w; w = alignp(w + (size_t)n * 4, 256);
    u32*   tmp      = (u32*)w;   w = alignp(w + (size_t)NBUK * CAP * 4, 256);
    u32*   es       = (u32*)w;   w = alignp(w + (size_t)EN * 4, 256);
    u16*   w1p      = (u16*)w;   w = alignp(w + (size_t)2 * 8 * 4 * 64 * 8 * 2, 256);
    u16*   w2p      = (u16*)w;   w = alignp(w + (size_t)2 * 4 * 4 * 64 * 8 * 2, 256);
    u16*   h1b      = (u16*)w;   w = alignp(w + (size_t)n * 128 * 2, 256);
    u16*   a1b      = (u16*)w;   w = alignp(w + (size_t)n * 128 * 2, 256);
    u16*   h2b      = h1b;  // reuse: h1b dead after first aggregation

    k_zero<<<1, 256, 0, stream>>>(bcur, NBUK);
    k_binA<<<(EN + EPB - 1) / EPB, 256, 0, stream>>>(ei, bcur, tmp, E, n, NBUK);
    k_scanb<<<1, 256, 0, stream>>>(bcur, bbase, row_ptr, NBUK, n);
    k_binB1<<<NBUK, 256, 0, stream>>>(tmp, bcur, bbase, row_ptr, dis, n);
    k_binB2<<<NBUK, 256, 0, stream>>>(tmp, bcur, bbase, dis, es, n);
    k_packW<128><<<(2 * 8 * 4 * 64 + 255) / 256, 256, 0, stream>>>(W1, w1p);
    k_packW<64><<<(2 * 4 * 4 * 64 + 255) / 256, 256, 0, stream>>>(W2, w2p);

    k_gemm1<<<GB, 256, 0, stream>>>(x, w1p, h1b, n);
    k_agg128<<<(n + 3) / 4, 256, 0, stream>>>(h1b, row_ptr, es, b1, a1b, n);
    k_gemm2<<<GB, 256, 0, stream>>>(a1b, w2p, h2b, n);
    k_agg64<<<(n + 3) / 4, 256, 0, stream>>>(h2b, row_ptr, es, b2, out, n);
}

// Round 15
// 149.987 us; speedup vs baseline: 1.2586x; 1.0343x over previous
//
#include <hip/hip_runtime.h>

typedef unsigned short u16;
typedef unsigned int u32;
typedef __attribute__((ext_vector_type(8))) short bf16x8;
typedef __attribute__((ext_vector_type(4))) float f32x4;

#define IN_F 128
#define CAP  8192   // record capacity per 256-node bucket (mean ~4.4K, +58 sigma)
#define EPB  8192   // edges per binA block

// ---------- helpers ----------
__device__ inline float bf2f(u16 v) {
    return __uint_as_float(((unsigned)v) << 16);
}
__device__ inline u16 f2bf(float f) {
    unsigned u = __float_as_uint(f);
    return (u16)((u + 0x7fffu + ((u >> 16) & 1u)) >> 16);
}

__device__ inline int block_scan_excl(int v, int* sdat) {
    int tid = threadIdx.x;
    sdat[tid] = v;
    __syncthreads();
#pragma unroll
    for (int off = 1; off < 256; off <<= 1) {
        int t = (tid >= off) ? sdat[tid - off] : 0;
        __syncthreads();
        sdat[tid] += t;
        __syncthreads();
    }
    return sdat[tid] - v;
}

// ---------------- setup: zero bcur + pack W1/W2 into MFMA B-fragment order --------
// Wp layout: Wp[((h*NCT+ct)*4+kt)*64 + l][r], h=0 hi, h=1 lo residual.

template<int M>
__device__ inline void packW_body(const float* __restrict__ W, u16* __restrict__ Wp, int t) {
    constexpr int NCT = M / 16;
    int l  = t & 63;
    int q  = t >> 6;
    int kt = q & 3;
    int q2 = q >> 2;
    int ct = q2 % NCT;
    int h  = q2 / NCT;
    int col   = 16 * ct + (l & 15);
    int krow0 = 32 * kt + 8 * (l >> 4);
    u16* outp = Wp + (size_t)t * 8;
#pragma unroll
    for (int r = 0; r < 8; ++r) {
        float w  = W[(size_t)(krow0 + r) * M + col];
        u16 hi   = f2bf(w);
        outp[r] = (h == 0) ? hi : f2bf(w - bf2f(hi));
    }
}

__global__ __launch_bounds__(256) void k_setup(const float* __restrict__ W1,
                                               const float* __restrict__ W2,
                                               u16* __restrict__ w1p,
                                               u16* __restrict__ w2p,
                                               int* bcur, int nbuk) {
    int t = blockIdx.x * 256 + threadIdx.x;
    if (t < nbuk) bcur[t] = 0;
    if (t < 2 * 8 * 4 * 64) packW_body<128>(W1, w1p, t);
    if (t < 2 * 4 * 4 * 64) packW_body<64>(W2, w2p, t);
}

// ---------------- CSR construction (block-aggregated binning) ----------------

// binA: block-aggregated scatter of {src16, dlocal8<<16} into per-bucket regions.
__global__ __launch_bounds__(256) void k_binA(const int* __restrict__ ei,
                                              int* bcur, u32* __restrict__ tmp,
                                              int E, int n, int nbuk) {
    __shared__ int hist[256];
    const int tid = threadIdx.x;
    const int EN = E + n;
    const int t0 = blockIdx.x * EPB;
    const int t1 = min(t0 + EPB, EN);
    hist[tid] = 0;
    __syncthreads();
    for (int t = t0 + tid; t < t1; t += 256) {
        int d = (t < E) ? ei[E + t] : (t - E);
        atomicAdd(&hist[d >> 8], 1);
    }
    __syncthreads();
    if (tid < nbuk) {
        int r = hist[tid];
        int g = (r > 0) ? atomicAdd(&bcur[tid], r) : 0;
        hist[tid] = tid * CAP + g;
    }
    __syncthreads();
    for (int t = t0 + tid; t < t1; t += 256) {
        int s, d;
        if (t < E) { s = ei[t]; d = ei[E + t]; }
        else       { s = t - E; d = s; }
        int bk = d >> 8;
        int pos = atomicAdd(&hist[bk], 1);
        if (pos < (bk + 1) * CAP)
            tmp[pos] = (u32)s | ((u32)(d & 255) << 16);
    }
}

// binB1: per bucket — inline bucket-base scan (over bcur), LDS degree count +
// scan -> row_ptr, dis. Last bucket writes row_ptr[n]. No global atomics.
__global__ __launch_bounds__(256) void k_binB1(const u32* __restrict__ tmp,
                                               const int* __restrict__ bcur,
                                               int* __restrict__ row_ptr,
                                               float* __restrict__ dis,
                                               int n, int nbuk) {
    __shared__ int sdat[256];
    __shared__ int cnt_l[256];
    __shared__ int s_gbase;
    const int b = blockIdx.x;
    const int tid = threadIdx.x;
    // bucket-base: exclusive scan over all bucket totals (nbuk <= 256)
    int v = (tid < nbuk) ? min(bcur[tid], CAP) : 0;
    int ex0 = block_scan_excl(v, sdat);
    if (tid == b) s_gbase = ex0;
    if (b == nbuk - 1 && tid == 0) row_ptr[n] = sdat[255];
    __syncthreads();
    const int gbase = s_gbase;
    const int total = min(bcur[b], CAP);
    const u32* rec0 = tmp + (size_t)b * CAP;
    cnt_l[tid] = 0;
    __syncthreads();
    for (int i = tid; i < total; i += 256)
        atomicAdd(&cnt_l[rec0[i] >> 16], 1);
    __syncthreads();
    int deg = cnt_l[tid];
    int ex = block_scan_excl(deg, sdat);
    int node = b * 256 + tid;
    if (node < n) {
        row_ptr[node] = gbase + ex;
        dis[node] = rsqrtf((float)deg);
    }
}

// binB2: per bucket — cursors seeded straight from row_ptr (no recount); place
// es32 records {src16 | bf16(dis[src]*dis[dst])<<16} via LDS cursors; copy out.
__global__ __launch_bounds__(256) void k_binB2(const u32* __restrict__ tmp,
                                               const int* __restrict__ bcur,
                                               const int* __restrict__ row_ptr,
                                               const float* __restrict__ dis,
                                               u32* __restrict__ es, int n) {
    __shared__ int lcur[256];
    __shared__ float ldis[256];
    __shared__ u32 es_lds[CAP];
    const int b = blockIdx.x;
    const int tid = threadIdx.x;
    const int total = min(bcur[b], CAP);
    const int node0 = b * 256;
    const int gbase = row_ptr[node0];   // == bucket base (exclusive scan, first node)
    int node = node0 + tid;
    lcur[tid] = (node < n) ? (row_ptr[node] - gbase) : 0;
    ldis[tid] = (node < n) ? dis[node] : 0.f;
    __syncthreads();
    const u32* rec0 = tmp + (size_t)b * CAP;
    for (int i = tid; i < total; i += 256) {
        u32 rec = rec0[i];
        int dl = rec >> 16;
        int s  = rec & 0xffff;
        float nrm = dis[s] * ldis[dl];
        int p = atomicAdd(&lcur[dl], 1);
        es_lds[p] = (u32)s | ((u32)f2bf(nrm) << 16);
    }
    __syncthreads();
    for (int i = tid; i < total; i += 256)
        es[gbase + i] = es_lds[i];
}

// ------- GEMM1: h1[n,128](bf16) = X[n,128](f32) @ W1, 3-term bf16 split --------------

__global__ __launch_bounds__(256) void k_gemm1(const float* __restrict__ X,
                                               const u16* __restrict__ Wp,
                                               u16* __restrict__ Y, int n) {
    constexpr int NCT = 8;
    constexpr int WPW = 2 * NCT * 4 * 64 * 8;
    __shared__ u16 wlds[WPW];
    for (int i = threadIdx.x; i < WPW / 8; i += 256)
        ((uint4*)wlds)[i] = ((const uint4*)Wp)[i];
    __syncthreads();
    const int wid = threadIdx.x >> 6;
    const int l   = threadIdx.x & 63;
    const int lr  = l & 15;
    const int lg  = l >> 4;
#pragma unroll
    for (int rt = 0; rt < 4; ++rt) {
        const int row0 = blockIdx.x * 256 + rt * 64 + wid * 16;
        const int arow = row0 + lr;
        const bool rowok = arow < n;
        const float* xr = X + (size_t)arow * 128;
        bf16x8 ahi[4], alo[4];
#pragma unroll
        for (int kt = 0; kt < 4; ++kt) {
            float v[8];
            if (rowok) {
                float4 p0 = *(const float4*)(xr + 32 * kt + 8 * lg);
                float4 p1 = *(const float4*)(xr + 32 * kt + 8 * lg + 4);
                v[0] = p0.x; v[1] = p0.y; v[2] = p0.z; v[3] = p0.w;
                v[4] = p1.x; v[5] = p1.y; v[6] = p1.z; v[7] = p1.w;
            } else {
#pragma unroll
                for (int r = 0; r < 8; ++r) v[r] = 0.f;
            }
#pragma unroll
            for (int r = 0; r < 8; ++r) {
                u16 hi = f2bf(v[r]);
                ahi[kt][r] = (short)hi;
                alo[kt][r] = (short)f2bf(v[r] - bf2f(hi));
            }
        }
#pragma unroll
        for (int ct = 0; ct < NCT; ++ct) {
            f32x4 acc = {0.f, 0.f, 0.f, 0.f};
            const u16* whi = wlds + (size_t)(ct * 4) * 512 + l * 8;
            const u16* wlo = whi + (size_t)NCT * 4 * 512;
#pragma unroll
            for (int kt = 0; kt < 4; ++kt) {
                bf16x8 bh = *(const bf16x8*)(whi + kt * 512);
                bf16x8 bl = *(const bf16x8*)(wlo + kt * 512);
                acc = __builtin_amdgcn_mfma_f32_16x16x32_bf16(ahi[kt], bh, acc, 0, 0, 0);
                acc = __builtin_amdgcn_mfma_f32_16x16x32_bf16(alo[kt], bh, acc, 0, 0, 0);
                acc = __builtin_amdgcn_mfma_f32_16x16x32_bf16(ahi[kt], bl, acc, 0, 0, 0);
            }
#pragma unroll
            for (int r = 0; r < 4; ++r) {
                int row = row0 + lg * 4 + r;
                if (row < n) Y[(size_t)row * 128 + 16 * ct + lr] = f2bf(acc[r]);
            }
        }
    }
}

// ------- GEMM2: h2[n,64](bf16) = a1[n,128](bf16) @ W2, 2-term (A exact bf16) --------

__global__ __launch_bounds__(256) void k_gemm2(const u16* __restrict__ A,
                                               const u16* __restrict__ Wp,
                                               u16* __restrict__ Y, int n) {
    constexpr int NCT = 4;
    constexpr int WPW = 2 * NCT * 4 * 64 * 8;
    __shared__ u16 wlds[WPW];
    for (int i = threadIdx.x; i < WPW / 8; i += 256)
        ((uint4*)wlds)[i] = ((const uint4*)Wp)[i];
    __syncthreads();
    const int wid = threadIdx.x >> 6;
    const int l   = threadIdx.x & 63;
    const int lr  = l & 15;
    const int lg  = l >> 4;
#pragma unroll
    for (int rt = 0; rt < 4; ++rt) {
        const int row0 = blockIdx.x * 256 + rt * 64 + wid * 16;
        const int arow = row0 + lr;
        const bool rowok = arow < n;
        bf16x8 a[4];
#pragma unroll
        for (int kt = 0; kt < 4; ++kt) {
            if (rowok) {
                a[kt] = *(const bf16x8*)(A + (size_t)arow * 128 + 32 * kt + 8 * lg);
            } else {
#pragma unroll
                for (int r = 0; r < 8; ++r) a[kt][r] = 0;
            }
        }
#pragma unroll
        for (int ct = 0; ct < NCT; ++ct) {
            f32x4 acc = {0.f, 0.f, 0.f, 0.f};
            const u16* whi = wlds + (size_t)(ct * 4) * 512 + l * 8;
            const u16* wlo = whi + (size_t)NCT * 4 * 512;
#pragma unroll
            for (int kt = 0; kt < 4; ++kt) {
                bf16x8 bh = *(const bf16x8*)(whi + kt * 512);
                bf16x8 bl = *(const bf16x8*)(wlo + kt * 512);
                acc = __builtin_amdgcn_mfma_f32_16x16x32_bf16(a[kt], bh, acc, 0, 0, 0);
                acc = __builtin_amdgcn_mfma_f32_16x16x32_bf16(a[kt], bl, acc, 0, 0, 0);
            }
#pragma unroll
            for (int r = 0; r < 4; ++r) {
                int row = row0 + lg * 4 + r;
                if (row < n) Y[(size_t)row * 64 + 16 * ct + lr] = f2bf(acc[r]);
            }
        }
    }
}

// ------- agg128: 2 half-wave edge streams x 8-unroll (16 edges in flight) ----------
// record r: src = r&0xffff, w = bf16(dis[s]*dis[d]) in high 16 bits.

__global__ __launch_bounds__(256) void k_agg128(const u16* __restrict__ h,
                                                const int* __restrict__ row_ptr,
                                                const u32* __restrict__ es,
                                                const float* __restrict__ bias,
                                                u16* __restrict__ out, int n) {
    int node = blockIdx.x * 4 + (threadIdx.x >> 6);
    if (node >= n) return;
    int lane = threadIdx.x & 63;
    int half = lane >> 5;
    int li   = lane & 31;      // cols 4li..4li+3
    int beg = row_ptr[node], end = row_ptr[node + 1];
    const u16* hp = h + li * 4;
    float a0 = 0.f, a1 = 0.f, a2 = 0.f, a3 = 0.f;
    float b0 = 0.f, b1 = 0.f, b2 = 0.f, b3 = 0.f;
    float c0 = 0.f, c1 = 0.f, c2 = 0.f, c3 = 0.f;
    float d0 = 0.f, d1 = 0.f, d2 = 0.f, d3 = 0.f;
    int e = beg + half;
    for (; e + 14 < end; e += 16) {
        u32 r0 = es[e],      r1 = es[e + 2],  r2 = es[e + 4],  r3 = es[e + 6];
        u32 r4 = es[e + 8],  r5 = es[e + 10], r6 = es[e + 12], r7 = es[e + 14];
        ushort4 v0 = *(const ushort4*)(hp + (size_t)(r0 & 0xffff) * 128);
        ushort4 v1 = *(const ushort4*)(hp + (size_t)(r1 & 0xffff) * 128);
        ushort4 v2 = *(const ushort4*)(hp + (size_t)(r2 & 0xffff) * 128);
        ushort4 v3 = *(const ushort4*)(hp + (size_t)(r3 & 0xffff) * 128);
        ushort4 v4 = *(const ushort4*)(hp + (size_t)(r4 & 0xffff) * 128);
        ushort4 v5 = *(const ushort4*)(hp + (size_t)(r5 & 0xffff) * 128);
        ushort4 v6 = *(const ushort4*)(hp + (size_t)(r6 & 0xffff) * 128);
        ushort4 v7 = *(const ushort4*)(hp + (size_t)(r7 & 0xffff) * 128);
        float w0 = bf2f((u16)(r0 >> 16)), w1 = bf2f((u16)(r1 >> 16));
        float w2 = bf2f((u16)(r2 >> 16)), w3 = bf2f((u16)(r3 >> 16));
        float w4 = bf2f((u16)(r4 >> 16)), w5 = bf2f((u16)(r5 >> 16));
        float w6 = bf2f((u16)(r6 >> 16)), w7 = bf2f((u16)(r7 >> 16));
        a0 += w0 * bf2f(v0.x); a1 += w0 * bf2f(v0.y);
        a2 += w0 * bf2f(v0.z); a3 += w0 * bf2f(v0.w);
        b0 += w1 * bf2f(v1.x); b1 += w1 * bf2f(v1.y);
        b2 += w1 * bf2f(v1.z); b3 += w1 * bf2f(v1.w);
        c0 += w2 * bf2f(v2.x); c1 += w2 * bf2f(v2.y);
        c2 += w2 * bf2f(v2.z); c3 += w2 * bf2f(v2.w);
        d0 += w3 * bf2f(v3.x); d1 += w3 * bf2f(v3.y);
        d2 += w3 * bf2f(v3.z); d3 += w3 * bf2f(v3.w);
        a0 += w4 * bf2f(v4.x); a1 += w4 * bf2f(v4.y);
        a2 += w4 * bf2f(v4.z); a3 += w4 * bf2f(v4.w);
        b0 += w5 * bf2f(v5.x); b1 += w5 * bf2f(v5.y);
        b2 += w5 * bf2f(v5.z); b3 += w5 * bf2f(v5.w);
        c0 += w6 * bf2f(v6.x); c1 += w6 * bf2f(v6.y);
        c2 += w6 * bf2f(v6.z); c3 += w6 * bf2f(v6.w);
        d0 += w7 * bf2f(v7.x); d1 += w7 * bf2f(v7.y);
        d2 += w7 * bf2f(v7.z); d3 += w7 * bf2f(v7.w);
    }
    for (; e < end; e += 2) {
        u32 r0 = es[e];
        float w0 = bf2f((u16)(r0 >> 16));
        ushort4 v0 = *(const ushort4*)(hp + (size_t)(r0 & 0xffff) * 128);
        a0 += w0 * bf2f(v0.x); a1 += w0 * bf2f(v0.y);
        a2 += w0 * bf2f(v0.z); a3 += w0 * bf2f(v0.w);
    }
    a0 = (a0 + b0) + (c0 + d0);
    a1 = (a1 + b1) + (c1 + d1);
    a2 = (a2 + b2) + (c2 + d2);
    a3 = (a3 + b3) + (c3 + d3);
    a0 += __shfl_xor(a0, 32, 64);
    a1 += __shfl_xor(a1, 32, 64);
    a2 += __shfl_xor(a2, 32, 64);
    a3 += __shfl_xor(a3, 32, 64);
    if (half == 0) {
        float4 bv = *(const float4*)(bias + 4 * li);
        a0 = fmaxf(a0 + bv.x, 0.f);
        a1 = fmaxf(a1 + bv.y, 0.f);
        a2 = fmaxf(a2 + bv.z, 0.f);
        a3 = fmaxf(a3 + bv.w, 0.f);
        ushort4 o;
        o.x = f2bf(a0); o.y = f2bf(a1); o.z = f2bf(a2); o.w = f2bf(a3);
        *(ushort4*)(out + (size_t)node * 128 + 4 * li) = o;
    }
}

// ------- agg64: 4 quarter-wave edge streams x 4-unroll (16 edges in flight) --------

__global__ __launch_bounds__(256) void k_agg64(const u16* __restrict__ h,
                                               const int* __restrict__ row_ptr,
                                               const u32* __restrict__ es,
                                               const float* __restrict__ bias,
                                               float* __restrict__ out, int n) {
    int node = blockIdx.x * 4 + (threadIdx.x >> 6);
    if (node >= n) return;
    int lane = threadIdx.x & 63;
    int q  = lane >> 4;
    int li = lane & 15;        // cols 4li..4li+3
    int beg = row_ptr[node], end = row_ptr[node + 1];
    const u16* hp = h + li * 4;
    float a0 = 0.f, a1 = 0.f, a2 = 0.f, a3 = 0.f;
    float b0 = 0.f, b1 = 0.f, b2 = 0.f, b3 = 0.f;
    float c0 = 0.f, c1 = 0.f, c2 = 0.f, c3 = 0.f;
    float d0 = 0.f, d1 = 0.f, d2 = 0.f, d3 = 0.f;
    int e = beg + q;
    for (; e + 12 < end; e += 16) {
        u32 r0 = es[e], r1 = es[e + 4], r2 = es[e + 8], r3 = es[e + 12];
        ushort4 v0 = *(const ushort4*)(hp + (size_t)(r0 & 0xffff) * 64);
        ushort4 v1 = *(const ushort4*)(hp + (size_t)(r1 & 0xffff) * 64);
        ushort4 v2 = *(const ushort4*)(hp + (size_t)(r2 & 0xffff) * 64);
        ushort4 v3 = *(const ushort4*)(hp + (size_t)(r3 & 0xffff) * 64);
        float w0 = bf2f((u16)(r0 >> 16)), w1 = bf2f((u16)(r1 >> 16));
        float w2 = bf2f((u16)(r2 >> 16)), w3 = bf2f((u16)(r3 >> 16));
        a0 += w0 * bf2f(v0.x); a1 += w0 * bf2f(v0.y);
        a2 += w0 * bf2f(v0.z); a3 += w0 * bf2f(v0.w);
        b0 += w1 * bf2f(v1.x); b1 += w1 * bf2f(v1.y);
        b2 += w1 * bf2f(v1.z); b3 += w1 * bf2f(v1.w);
        c0 += w2 * bf2f(v2.x); c1 += w2 * bf2f(v2.y);
        c2 += w2 * bf2f(v2.z); c3 += w2 * bf2f(v2.w);
        d0 += w3 * bf2f(v3.x); d1 += w3 * bf2f(v3.y);
        d2 += w3 * bf2f(v3.z); d3 += w3 * bf2f(v3.w);
    }
    for (; e < end; e += 4) {
        u32 r0 = es[e];
        float w0 = bf2f((u16)(r0 >> 16));
        ushort4 v0 = *(const ushort4*)(hp + (size_t)(r0 & 0xffff) * 64);
        a0 += w0 * bf2f(v0.x); a1 += w0 * bf2f(v0.y);
        a2 += w0 * bf2f(v0.z); a3 += w0 * bf2f(v0.w);
    }
    a0 = (a0 + b0) + (c0 + d0);
    a1 = (a1 + b1) + (c1 + d1);
    a2 = (a2 + b2) + (c2 + d2);
    a3 = (a3 + b3) + (c3 + d3);
    a0 += __shfl_xor(a0, 16, 64); a0 += __shfl_xor(a0, 32, 64);
    a1 += __shfl_xor(a1, 16, 64); a1 += __shfl_xor(a1, 32, 64);
    a2 += __shfl_xor(a2, 16, 64); a2 += __shfl_xor(a2, 32, 64);
    a3 += __shfl_xor(a3, 16, 64); a3 += __shfl_xor(a3, 32, 64);
    if (q == 0) {
        float4 bv = *(const float4*)(bias + 4 * li);
        float4 o;
        o.x = a0 + bv.x; o.y = a1 + bv.y; o.z = a2 + bv.z; o.w = a3 + bv.w;
        *(float4*)(out + (size_t)node * 64 + 4 * li) = o;
    }
}

// ---------------- launch ----------------

static inline char* alignp(char* p, size_t a) {
    return (char*)(((uintptr_t)p + a - 1) & ~(uintptr_t)(a - 1));
}

extern "C" void kernel_launch(void* const* d_in, const int* in_sizes, int n_in,
                              void* d_out, int out_size, void* d_ws, size_t ws_size,
                              hipStream_t stream) {
    const float* x  = (const float*)d_in[0];
    const int*   ei = (const int*)d_in[1];
    const float* W1 = (const float*)d_in[2];
    const float* b1 = (const float*)d_in[3];
    const float* W2 = (const float*)d_in[4];
    const float* b2 = (const float*)d_in[5];
    float* out = (float*)d_out;

    const int n    = in_sizes[0] / IN_F;
    const int E    = in_sizes[1] / 2;
    const int EN   = E + n;
    const int NBUK = (n + 255) / 256;
    const int GB   = (n + 255) / 256;

    char* w = (char*)d_ws;
    int*   row_ptr  = (int*)w;   w = alignp(w + (size_t)(n + 1) * 4, 256);
    int*   bcur     = (int*)w;   w = alignp(w + (size_t)NBUK * 4, 256);
    float* dis      = (float*)w; w = alignp(w + (size_t)n * 4, 256);
    u32*   tmp      = (u32*)w;   w = alignp(w + (size_t)NBUK * CAP * 4, 256);
    u32*   es       = (u32*)w;   w = alignp(w + (size_t)EN * 4, 256);
    u16*   w1p      = (u16*)w;   w = alignp(w + (size_t)2 * 8 * 4 * 64 * 8 * 2, 256);
    u16*   w2p      = (u16*)w;   w = alignp(w + (size_t)2 * 4 * 4 * 64 * 8 * 2, 256);
    u16*   h1b      = (u16*)w;   w = alignp(w + (size_t)n * 128 * 2, 256);
    u16*   a1b      = (u16*)w;   w = alignp(w + (size_t)n * 128 * 2, 256);
    u16*   h2b      = h1b;  // reuse: h1b dead after first aggregation

    k_setup<<<16, 256, 0, stream>>>(W1, W2, w1p, w2p, bcur, NBUK);
    k_binA<<<(EN + EPB - 1) / EPB, 256, 0, stream>>>(ei, bcur, tmp, E, n, NBUK);
    k_binB1<<<NBUK, 256, 0, stream>>>(tmp, bcur, row_ptr, dis, n, NBUK);
    k_binB2<<<NBUK, 256, 0, stream>>>(tmp, bcur, row_ptr, dis, es, n);

    k_gemm1<<<GB, 256, 0, stream>>>(x, w1p, h1b, n);
    k_agg128<<<(n + 3) / 4, 256, 0, stream>>>(h1b, row_ptr, es, b1, a1b, n);
    k_gemm2<<<GB, 256, 0, stream>>>(a1b, w2p, h2b, n);
    k_agg64<<<(n + 3) / 4, 256, 0, stream>>>(h2b, row_ptr, es, b2, out, n);
}

// Round 16
// 131.352 us; speedup vs baseline: 1.4372x; 1.1419x over previous
//
#include <hip/hip_runtime.h>

typedef unsigned short u16;
typedef unsigned int u32;
typedef __attribute__((ext_vector_type(8))) short bf16x8;
typedef __attribute__((ext_vector_type(4))) float f32x4;

#define IN_F 128
#define CAP  8192   // record capacity per 256-node bucket (mean ~4.4K, +58 sigma)
#define EPB  8192   // edges per binA block

// ---------- helpers ----------
__device__ inline float bf2f(u16 v) {
    return __uint_as_float(((unsigned)v) << 16);
}
__device__ inline u16 f2bf(float f) {
    unsigned u = __float_as_uint(f);
    return (u16)((u + 0x7fffu + ((u >> 16) & 1u)) >> 16);
}

__device__ inline int block_scan_excl(int v, int* sdat) {
    int tid = threadIdx.x;
    sdat[tid] = v;
    __syncthreads();
#pragma unroll
    for (int off = 1; off < 256; off <<= 1) {
        int t = (tid >= off) ? sdat[tid - off] : 0;
        __syncthreads();
        sdat[tid] += t;
        __syncthreads();
    }
    return sdat[tid] - v;
}

// ---------------- setup: zero bcur + pack W1/W2 into MFMA B-fragment order --------
// Wp layout: Wp[((h*NCT+ct)*4+kt)*64 + l][r], h=0 hi, h=1 lo residual.

template<int M>
__device__ inline void packW_body(const float* __restrict__ W, u16* __restrict__ Wp, int t) {
    constexpr int NCT = M / 16;
    int l  = t & 63;
    int q  = t >> 6;
    int kt = q & 3;
    int q2 = q >> 2;
    int ct = q2 % NCT;
    int h  = q2 / NCT;
    int col   = 16 * ct + (l & 15);
    int krow0 = 32 * kt + 8 * (l >> 4);
    u16* outp = Wp + (size_t)t * 8;
#pragma unroll
    for (int r = 0; r < 8; ++r) {
        float w  = W[(size_t)(krow0 + r) * M + col];
        u16 hi   = f2bf(w);
        outp[r] = (h == 0) ? hi : f2bf(w - bf2f(hi));
    }
}

__global__ __launch_bounds__(256) void k_setup(const float* __restrict__ W1,
                                               const float* __restrict__ W2,
                                               u16* __restrict__ w1p,
                                               u16* __restrict__ w2p,
                                               int* bcur, int nbuk) {
    int t = blockIdx.x * 256 + threadIdx.x;
    if (t < nbuk) bcur[t] = 0;
    if (t < 2 * 8 * 4 * 64) packW_body<128>(W1, w1p, t);
    if (t < 2 * 4 * 4 * 64) packW_body<64>(W2, w2p, t);
}

// ---------------- fused: gemm1 (blocks [0,gb)) || binA (blocks [gb, gb+nblkA)) ------
// gemm1: h1[n,128](bf16) = X[n,128](f32) @ W1, 3-term bf16 split, 256 rows/block.
// binA:  block-aggregated scatter of {src16, dlocal8<<16} into per-bucket regions;
//        per-edge atomics LDS-only, one global atomic per (block,bucket).

__global__ __launch_bounds__(256) void k_ag1(const float* __restrict__ X,
                                             const u16* __restrict__ Wp,
                                             u16* __restrict__ Y,
                                             const int* __restrict__ ei,
                                             int* bcur, u32* __restrict__ tmp,
                                             int E, int n, int nbuk, int gb) {
    constexpr int NCT = 8;
    constexpr int WPW = 2 * NCT * 4 * 64 * 8;
    __shared__ u16 wlds[WPW];     // 64 KB (gemm1 branch)
    __shared__ int hist[256];     // 1 KB  (binA branch)
    const int tid = threadIdx.x;

    if (blockIdx.x < gb) {
        // ---------------- gemm1 body ----------------
        for (int i = tid; i < WPW / 8; i += 256)
            ((uint4*)wlds)[i] = ((const uint4*)Wp)[i];
        __syncthreads();
        const int wid = tid >> 6;
        const int l   = tid & 63;
        const int lr  = l & 15;
        const int lg  = l >> 4;
#pragma unroll
        for (int rt = 0; rt < 4; ++rt) {
            const int row0 = blockIdx.x * 256 + rt * 64 + wid * 16;
            const int arow = row0 + lr;
            const bool rowok = arow < n;
            const float* xr = X + (size_t)arow * 128;
            bf16x8 ahi[4], alo[4];
#pragma unroll
            for (int kt = 0; kt < 4; ++kt) {
                float v[8];
                if (rowok) {
                    float4 p0 = *(const float4*)(xr + 32 * kt + 8 * lg);
                    float4 p1 = *(const float4*)(xr + 32 * kt + 8 * lg + 4);
                    v[0] = p0.x; v[1] = p0.y; v[2] = p0.z; v[3] = p0.w;
                    v[4] = p1.x; v[5] = p1.y; v[6] = p1.z; v[7] = p1.w;
                } else {
#pragma unroll
                    for (int r = 0; r < 8; ++r) v[r] = 0.f;
                }
#pragma unroll
                for (int r = 0; r < 8; ++r) {
                    u16 hi = f2bf(v[r]);
                    ahi[kt][r] = (short)hi;
                    alo[kt][r] = (short)f2bf(v[r] - bf2f(hi));
                }
            }
#pragma unroll
            for (int ct = 0; ct < NCT; ++ct) {
                f32x4 acc = {0.f, 0.f, 0.f, 0.f};
                const u16* whi = wlds + (size_t)(ct * 4) * 512 + l * 8;
                const u16* wlo = whi + (size_t)NCT * 4 * 512;
#pragma unroll
                for (int kt = 0; kt < 4; ++kt) {
                    bf16x8 bh = *(const bf16x8*)(whi + kt * 512);
                    bf16x8 bl = *(const bf16x8*)(wlo + kt * 512);
                    acc = __builtin_amdgcn_mfma_f32_16x16x32_bf16(ahi[kt], bh, acc, 0, 0, 0);
                    acc = __builtin_amdgcn_mfma_f32_16x16x32_bf16(alo[kt], bh, acc, 0, 0, 0);
                    acc = __builtin_amdgcn_mfma_f32_16x16x32_bf16(ahi[kt], bl, acc, 0, 0, 0);
                }
#pragma unroll
                for (int r = 0; r < 4; ++r) {
                    int row = row0 + lg * 4 + r;
                    if (row < n) Y[(size_t)row * 128 + 16 * ct + lr] = f2bf(acc[r]);
                }
            }
        }
    } else {
        // ---------------- binA body ----------------
        const int b = blockIdx.x - gb;
        const int EN = E + n;
        const int t0 = b * EPB;
        const int t1 = min(t0 + EPB, EN);
        hist[tid] = 0;
        __syncthreads();
        for (int t = t0 + tid; t < t1; t += 256) {
            int d = (t < E) ? ei[E + t] : (t - E);
            atomicAdd(&hist[d >> 8], 1);
        }
        __syncthreads();
        if (tid < nbuk) {
            int r = hist[tid];
            int g = (r > 0) ? atomicAdd(&bcur[tid], r) : 0;
            hist[tid] = tid * CAP + g;
        }
        __syncthreads();
        for (int t = t0 + tid; t < t1; t += 256) {
            int s, d;
            if (t < E) { s = ei[t]; d = ei[E + t]; }
            else       { s = t - E; d = s; }
            int bk = d >> 8;
            int pos = atomicAdd(&hist[bk], 1);
            if (pos < (bk + 1) * CAP)
                tmp[pos] = (u32)s | ((u32)(d & 255) << 16);
        }
    }
}

// binB1: per bucket — inline bucket-base scan (over bcur), LDS degree count +
// scan -> row_ptr, dis. Last bucket writes row_ptr[n]. No global atomics.
__global__ __launch_bounds__(256) void k_binB1(const u32* __restrict__ tmp,
                                               const int* __restrict__ bcur,
                                               int* __restrict__ row_ptr,
                                               float* __restrict__ dis,
                                               int n, int nbuk) {
    __shared__ int sdat[256];
    __shared__ int cnt_l[256];
    __shared__ int s_gbase;
    const int b = blockIdx.x;
    const int tid = threadIdx.x;
    int v = (tid < nbuk) ? min(bcur[tid], CAP) : 0;
    int ex0 = block_scan_excl(v, sdat);
    if (tid == b) s_gbase = ex0;
    if (b == nbuk - 1 && tid == 0) row_ptr[n] = sdat[255];
    __syncthreads();
    const int gbase = s_gbase;
    const int total = min(bcur[b], CAP);
    const u32* rec0 = tmp + (size_t)b * CAP;
    cnt_l[tid] = 0;
    __syncthreads();
    for (int i = tid; i < total; i += 256)
        atomicAdd(&cnt_l[rec0[i] >> 16], 1);
    __syncthreads();
    int deg = cnt_l[tid];
    int ex = block_scan_excl(deg, sdat);
    int node = b * 256 + tid;
    if (node < n) {
        row_ptr[node] = gbase + ex;
        dis[node] = rsqrtf((float)deg);
    }
}

// binB2: per bucket — cursors seeded straight from row_ptr (no recount); place
// es32 records {src16 | bf16(dis[src]*dis[dst])<<16} via LDS cursors; copy out.
__global__ __launch_bounds__(256) void k_binB2(const u32* __restrict__ tmp,
                                               const int* __restrict__ bcur,
                                               const int* __restrict__ row_ptr,
                                               const float* __restrict__ dis,
                                               u32* __restrict__ es, int n) {
    __shared__ int lcur[256];
    __shared__ float ldis[256];
    __shared__ u32 es_lds[CAP];
    const int b = blockIdx.x;
    const int tid = threadIdx.x;
    const int total = min(bcur[b], CAP);
    const int node0 = b * 256;
    const int gbase = row_ptr[node0];
    int node = node0 + tid;
    lcur[tid] = (node < n) ? (row_ptr[node] - gbase) : 0;
    ldis[tid] = (node < n) ? dis[node] : 0.f;
    __syncthreads();
    const u32* rec0 = tmp + (size_t)b * CAP;
    for (int i = tid; i < total; i += 256) {
        u32 rec = rec0[i];
        int dl = rec >> 16;
        int s  = rec & 0xffff;
        float nrm = dis[s] * ldis[dl];
        int p = atomicAdd(&lcur[dl], 1);
        es_lds[p] = (u32)s | ((u32)f2bf(nrm) << 16);
    }
    __syncthreads();
    for (int i = tid; i < total; i += 256)
        es[gbase + i] = es_lds[i];
}

// ------- GEMM2: h2[n,64](bf16) = a1[n,128](bf16) @ W2, 2-term (A exact bf16) --------

__global__ __launch_bounds__(256) void k_gemm2(const u16* __restrict__ A,
                                               const u16* __restrict__ Wp,
                                               u16* __restrict__ Y, int n) {
    constexpr int NCT = 4;
    constexpr int WPW = 2 * NCT * 4 * 64 * 8;
    __shared__ u16 wlds[WPW];
    for (int i = threadIdx.x; i < WPW / 8; i += 256)
        ((uint4*)wlds)[i] = ((const uint4*)Wp)[i];
    __syncthreads();
    const int wid = threadIdx.x >> 6;
    const int l   = threadIdx.x & 63;
    const int lr  = l & 15;
    const int lg  = l >> 4;
#pragma unroll
    for (int rt = 0; rt < 4; ++rt) {
        const int row0 = blockIdx.x * 256 + rt * 64 + wid * 16;
        const int arow = row0 + lr;
        const bool rowok = arow < n;
        bf16x8 a[4];
#pragma unroll
        for (int kt = 0; kt < 4; ++kt) {
            if (rowok) {
                a[kt] = *(const bf16x8*)(A + (size_t)arow * 128 + 32 * kt + 8 * lg);
            } else {
#pragma unroll
                for (int r = 0; r < 8; ++r) a[kt][r] = 0;
            }
        }
#pragma unroll
        for (int ct = 0; ct < NCT; ++ct) {
            f32x4 acc = {0.f, 0.f, 0.f, 0.f};
            const u16* whi = wlds + (size_t)(ct * 4) * 512 + l * 8;
            const u16* wlo = whi + (size_t)NCT * 4 * 512;
#pragma unroll
            for (int kt = 0; kt < 4; ++kt) {
                bf16x8 bh = *(const bf16x8*)(whi + kt * 512);
                bf16x8 bl = *(const bf16x8*)(wlo + kt * 512);
                acc = __builtin_amdgcn_mfma_f32_16x16x32_bf16(a[kt], bh, acc, 0, 0, 0);
                acc = __builtin_amdgcn_mfma_f32_16x16x32_bf16(a[kt], bl, acc, 0, 0, 0);
            }
#pragma unroll
            for (int r = 0; r < 4; ++r) {
                int row = row0 + lg * 4 + r;
                if (row < n) Y[(size_t)row * 64 + 16 * ct + lr] = f2bf(acc[r]);
            }
        }
    }
}

// ------- agg128: 2 half-wave edge streams x 8-unroll (16 edges in flight) ----------
// record r: src = r&0xffff, w = bf16(dis[s]*dis[d]) in high 16 bits.

__global__ __launch_bounds__(256) void k_agg128(const u16* __restrict__ h,
                                                const int* __restrict__ row_ptr,
                                                const u32* __restrict__ es,
                                                const float* __restrict__ bias,
                                                u16* __restrict__ out, int n) {
    int node = blockIdx.x * 4 + (threadIdx.x >> 6);
    if (node >= n) return;
    int lane = threadIdx.x & 63;
    int half = lane >> 5;
    int li   = lane & 31;      // cols 4li..4li+3
    int beg = row_ptr[node], end = row_ptr[node + 1];
    const u16* hp = h + li * 4;
    float a0 = 0.f, a1 = 0.f, a2 = 0.f, a3 = 0.f;
    float b0 = 0.f, b1 = 0.f, b2 = 0.f, b3 = 0.f;
    float c0 = 0.f, c1 = 0.f, c2 = 0.f, c3 = 0.f;
    float d0 = 0.f, d1 = 0.f, d2 = 0.f, d3 = 0.f;
    int e = beg + half;
    for (; e + 14 < end; e += 16) {
        u32 r0 = es[e],      r1 = es[e + 2],  r2 = es[e + 4],  r3 = es[e + 6];
        u32 r4 = es[e + 8],  r5 = es[e + 10], r6 = es[e + 12], r7 = es[e + 14];
        ushort4 v0 = *(const ushort4*)(hp + (size_t)(r0 & 0xffff) * 128);
        ushort4 v1 = *(const ushort4*)(hp + (size_t)(r1 & 0xffff) * 128);
        ushort4 v2 = *(const ushort4*)(hp + (size_t)(r2 & 0xffff) * 128);
        ushort4 v3 = *(const ushort4*)(hp + (size_t)(r3 & 0xffff) * 128);
        ushort4 v4 = *(const ushort4*)(hp + (size_t)(r4 & 0xffff) * 128);
        ushort4 v5 = *(const ushort4*)(hp + (size_t)(r5 & 0xffff) * 128);
        ushort4 v6 = *(const ushort4*)(hp + (size_t)(r6 & 0xffff) * 128);
        ushort4 v7 = *(const ushort4*)(hp + (size_t)(r7 & 0xffff) * 128);
        float w0 = bf2f((u16)(r0 >> 16)), w1 = bf2f((u16)(r1 >> 16));
        float w2 = bf2f((u16)(r2 >> 16)), w3 = bf2f((u16)(r3 >> 16));
        float w4 = bf2f((u16)(r4 >> 16)), w5 = bf2f((u16)(r5 >> 16));
        float w6 = bf2f((u16)(r6 >> 16)), w7 = bf2f((u16)(r7 >> 16));
        a0 += w0 * bf2f(v0.x); a1 += w0 * bf2f(v0.y);
        a2 += w0 * bf2f(v0.z); a3 += w0 * bf2f(v0.w);
        b0 += w1 * bf2f(v1.x); b1 += w1 * bf2f(v1.y);
        b2 += w1 * bf2f(v1.z); b3 += w1 * bf2f(v1.w);
        c0 += w2 * bf2f(v2.x); c1 += w2 * bf2f(v2.y);
        c2 += w2 * bf2f(v2.z); c3 += w2 * bf2f(v2.w);
        d0 += w3 * bf2f(v3.x); d1 += w3 * bf2f(v3.y);
        d2 += w3 * bf2f(v3.z); d3 += w3 * bf2f(v3.w);
        a0 += w4 * bf2f(v4.x); a1 += w4 * bf2f(v4.y);
        a2 += w4 * bf2f(v4.z); a3 += w4 * bf2f(v4.w);
        b0 += w5 * bf2f(v5.x); b1 += w5 * bf2f(v5.y);
        b2 += w5 * bf2f(v5.z); b3 += w5 * bf2f(v5.w);
        c0 += w6 * bf2f(v6.x); c1 += w6 * bf2f(v6.y);
        c2 += w6 * bf2f(v6.z); c3 += w6 * bf2f(v6.w);
        d0 += w7 * bf2f(v7.x); d1 += w7 * bf2f(v7.y);
        d2 += w7 * bf2f(v7.z); d3 += w7 * bf2f(v7.w);
    }
    for (; e < end; e += 2) {
        u32 r0 = es[e];
        float w0 = bf2f((u16)(r0 >> 16));
        ushort4 v0 = *(const ushort4*)(hp + (size_t)(r0 & 0xffff) * 128);
        a0 += w0 * bf2f(v0.x); a1 += w0 * bf2f(v0.y);
        a2 += w0 * bf2f(v0.z); a3 += w0 * bf2f(v0.w);
    }
    a0 = (a0 + b0) + (c0 + d0);
    a1 = (a1 + b1) + (c1 + d1);
    a2 = (a2 + b2) + (c2 + d2);
    a3 = (a3 + b3) + (c3 + d3);
    a0 += __shfl_xor(a0, 32, 64);
    a1 += __shfl_xor(a1, 32, 64);
    a2 += __shfl_xor(a2, 32, 64);
    a3 += __shfl_xor(a3, 32, 64);
    if (half == 0) {
        float4 bv = *(const float4*)(bias + 4 * li);
        a0 = fmaxf(a0 + bv.x, 0.f);
        a1 = fmaxf(a1 + bv.y, 0.f);
        a2 = fmaxf(a2 + bv.z, 0.f);
        a3 = fmaxf(a3 + bv.w, 0.f);
        ushort4 o;
        o.x = f2bf(a0); o.y = f2bf(a1); o.z = f2bf(a2); o.w = f2bf(a3);
        *(ushort4*)(out + (size_t)node * 128 + 4 * li) = o;
    }
}

// ------- agg64: 4 quarter-wave edge streams x 4-unroll (16 edges in flight) --------

__global__ __launch_bounds__(256) void k_agg64(const u16* __restrict__ h,
                                               const int* __restrict__ row_ptr,
                                               const u32* __restrict__ es,
                                               const float* __restrict__ bias,
                                               float* __restrict__ out, int n) {
    int node = blockIdx.x * 4 + (threadIdx.x >> 6);
    if (node >= n) return;
    int lane = threadIdx.x & 63;
    int q  = lane >> 4;
    int li = lane & 15;        // cols 4li..4li+3
    int beg = row_ptr[node], end = row_ptr[node + 1];
    const u16* hp = h + li * 4;
    float a0 = 0.f, a1 = 0.f, a2 = 0.f, a3 = 0.f;
    float b0 = 0.f, b1 = 0.f, b2 = 0.f, b3 = 0.f;
    float c0 = 0.f, c1 = 0.f, c2 = 0.f, c3 = 0.f;
    float d0 = 0.f, d1 = 0.f, d2 = 0.f, d3 = 0.f;
    int e = beg + q;
    for (; e + 12 < end; e += 16) {
        u32 r0 = es[e], r1 = es[e + 4], r2 = es[e + 8], r3 = es[e + 12];
        ushort4 v0 = *(const ushort4*)(hp + (size_t)(r0 & 0xffff) * 64);
        ushort4 v1 = *(const ushort4*)(hp + (size_t)(r1 & 0xffff) * 64);
        ushort4 v2 = *(const ushort4*)(hp + (size_t)(r2 & 0xffff) * 64);
        ushort4 v3 = *(const ushort4*)(hp + (size_t)(r3 & 0xffff) * 64);
        float w0 = bf2f((u16)(r0 >> 16)), w1 = bf2f((u16)(r1 >> 16));
        float w2 = bf2f((u16)(r2 >> 16)), w3 = bf2f((u16)(r3 >> 16));
        a0 += w0 * bf2f(v0.x); a1 += w0 * bf2f(v0.y);
        a2 += w0 * bf2f(v0.z); a3 += w0 * bf2f(v0.w);
        b0 += w1 * bf2f(v1.x); b1 += w1 * bf2f(v1.y);
        b2 += w1 * bf2f(v1.z); b3 += w1 * bf2f(v1.w);
        c0 += w2 * bf2f(v2.x); c1 += w2 * bf2f(v2.y);
        c2 += w2 * bf2f(v2.z); c3 += w2 * bf2f(v2.w);
        d0 += w3 * bf2f(v3.x); d1 += w3 * bf2f(v3.y);
        d2 += w3 * bf2f(v3.z); d3 += w3 * bf2f(v3.w);
    }
    for (; e < end; e += 4) {
        u32 r0 = es[e];
        float w0 = bf2f((u16)(r0 >> 16));
        ushort4 v0 = *(const ushort4*)(hp + (size_t)(r0 & 0xffff) * 64);
        a0 += w0 * bf2f(v0.x); a1 += w0 * bf2f(v0.y);
        a2 += w0 * bf2f(v0.z); a3 += w0 * bf2f(v0.w);
    }
    a0 = (a0 + b0) + (c0 + d0);
    a1 = (a1 + b1) + (c1 + d1);
    a2 = (a2 + b2) + (c2 + d2);
    a3 = (a3 + b3) + (c3 + d3);
    a0 += __shfl_xor(a0, 16, 64); a0 += __shfl_xor(a0, 32, 64);
    a1 += __shfl_xor(a1, 16, 64); a1 += __shfl_xor(a1, 32, 64);
    a2 += __shfl_xor(a2, 16, 64); a2 += __shfl_xor(a2, 32, 64);
    a3 += __shfl_xor(a3, 16, 64); a3 += __shfl_xor(a3, 32, 64);
    if (q == 0) {
        float4 bv = *(const float4*)(bias + 4 * li);
        float4 o;
        o.x = a0 + bv.x; o.y = a1 + bv.y; o.z = a2 + bv.z; o.w = a3 + bv.w;
        *(float4*)(out + (size_t)node * 64 + 4 * li) = o;
    }
}

// ---------------- launch ----------------

static inline char* alignp(char* p, size_t a) {
    return (char*)(((uintptr_t)p + a - 1) & ~(uintptr_t)(a - 1));
}

extern "C" void kernel_launch(void* const* d_in, const int* in_sizes, int n_in,
                              void* d_out, int out_size, void* d_ws, size_t ws_size,
                              hipStream_t stream) {
    const float* x  = (const float*)d_in[0];
    const int*   ei = (const int*)d_in[1];
    const float* W1 = (const float*)d_in[2];
    const float* b1 = (const float*)d_in[3];
    const float* W2 = (const float*)d_in[4];
    const float* b2 = (const float*)d_in[5];
    float* out = (float*)d_out;

    const int n     = in_sizes[0] / IN_F;
    const int E     = in_sizes[1] / 2;
    const int EN    = E + n;
    const int NBUK  = (n + 255) / 256;
    const int GB    = (n + 255) / 256;
    const int NBLKA = (EN + EPB - 1) / EPB;

    char* w = (char*)d_ws;
    int*   row_ptr  = (int*)w;   w = alignp(w + (size_t)(n + 1) * 4, 256);
    int*   bcur     = (int*)w;   w = alignp(w + (size_t)NBUK * 4, 256);
    float* dis      = (float*)w; w = alignp(w + (size_t)n * 4, 256);
    u32*   tmp      = (u32*)w;   w = alignp(w + (size_t)NBUK * CAP * 4, 256);
    u32*   es       = (u32*)w;   w = alignp(w + (size_t)EN * 4, 256);
    u16*   w1p      = (u16*)w;   w = alignp(w + (size_t)2 * 8 * 4 * 64 * 8 * 2, 256);
    u16*   w2p      = (u16*)w;   w = alignp(w + (size_t)2 * 4 * 4 * 64 * 8 * 2, 256);
    u16*   h1b      = (u16*)w;   w = alignp(w + (size_t)n * 128 * 2, 256);
    u16*   a1b      = (u16*)w;   w = alignp(w + (size_t)n * 128 * 2, 256);
    u16*   h2b      = h1b;  // reuse: h1b dead after first aggregation

    k_setup<<<16, 256, 0, stream>>>(W1, W2, w1p, w2p, bcur, NBUK);
    k_ag1<<<GB + NBLKA, 256, 0, stream>>>(x, w1p, h1b, ei, bcur, tmp, E, n, NBUK, GB);
    k_binB1<<<NBUK, 256, 0, stream>>>(tmp, bcur, row_ptr, dis, n, NBUK);
    k_binB2<<<NBUK, 256, 0, stream>>>(tmp, bcur, row_ptr, dis, es, n);

    k_agg128<<<(n + 3) / 4, 256, 0, stream>>>(h1b, row_ptr, es, b1, a1b, n);
    k_gemm2<<<GB, 256, 0, stream>>>(a1b, w2p, h2b, n);
    k_agg64<<<(n + 3) / 4, 256, 0, stream>>>(h2b, row_ptr, es, b2, out, n);
}

// Round 17
// 126.607 us; speedup vs baseline: 1.4911x; 1.0375x over previous
//
#include <hip/hip_runtime.h>

typedef unsigned short u16;
typedef unsigned int u32;
typedef __attribute__((ext_vector_type(8))) short bf16x8;
typedef __attribute__((ext_vector_type(4))) float f32x4;

#define IN_F 128
#define CAP  8192   // record capacity per 256-node bucket (mean ~4.4K, +58 sigma)
#define EPB  8192   // edges per binA block

// ---------- helpers ----------
__device__ inline float bf2f(u16 v) {
    return __uint_as_float(((unsigned)v) << 16);
}
__device__ inline u16 f2bf(float f) {
    unsigned u = __float_as_uint(f);
    return (u16)((u + 0x7fffu + ((u >> 16) & 1u)) >> 16);
}

__device__ inline int block_scan_excl(int v, int* sdat) {
    int tid = threadIdx.x;
    sdat[tid] = v;
    __syncthreads();
#pragma unroll
    for (int off = 1; off < 256; off <<= 1) {
        int t = (tid >= off) ? sdat[tid - off] : 0;
        __syncthreads();
        sdat[tid] += t;
        __syncthreads();
    }
    return sdat[tid] - v;
}

// ---------------- setup: zero bcur + pack W1/W2 into MFMA B-fragment order --------
// Wp layout: Wp[((h*NCT+ct)*4+kt)*64 + l][r], h=0 hi, h=1 lo residual.

template<int M>
__device__ inline void packW_body(const float* __restrict__ W, u16* __restrict__ Wp, int t) {
    constexpr int NCT = M / 16;
    int l  = t & 63;
    int q  = t >> 6;
    int kt = q & 3;
    int q2 = q >> 2;
    int ct = q2 % NCT;
    int h  = q2 / NCT;
    int col   = 16 * ct + (l & 15);
    int krow0 = 32 * kt + 8 * (l >> 4);
    u16* outp = Wp + (size_t)t * 8;
#pragma unroll
    for (int r = 0; r < 8; ++r) {
        float w  = W[(size_t)(krow0 + r) * M + col];
        u16 hi   = f2bf(w);
        outp[r] = (h == 0) ? hi : f2bf(w - bf2f(hi));
    }
}

__global__ __launch_bounds__(256) void k_setup(const float* __restrict__ W1,
                                               const float* __restrict__ W2,
                                               u16* __restrict__ w1p,
                                               u16* __restrict__ w2p,
                                               int* bcur, int nbuk) {
    int t = blockIdx.x * 256 + threadIdx.x;
    if (t < nbuk) bcur[t] = 0;
    if (t < 2 * 8 * 4 * 64) packW_body<128>(W1, w1p, t);
    if (t < 2 * 4 * 4 * 64) packW_body<64>(W2, w2p, t);
}

// ---------------- fused: gemm1 (blocks [0,gb)) || binA (blocks [gb, gb+nblkA)) ------
// gemm1: h1[n,128](bf16) = X[n,128](f32) @ W1, 3-term bf16 split, 256 rows/block.
// binA:  block-aggregated scatter of {src16, dlocal8<<16} into per-bucket regions;
//        int4-vectorized edge loads (4 edges/lane/iter), LDS-only per-edge atomics.

__global__ __launch_bounds__(256) void k_ag1(const float* __restrict__ X,
                                             const u16* __restrict__ Wp,
                                             u16* __restrict__ Y,
                                             const int* __restrict__ ei,
                                             int* bcur, u32* __restrict__ tmp,
                                             int E, int n, int nbuk, int gb) {
    constexpr int NCT = 8;
    constexpr int WPW = 2 * NCT * 4 * 64 * 8;
    __shared__ u16 wlds[WPW];     // 64 KB (gemm1 branch)
    __shared__ int hist[256];     // 1 KB  (binA branch)
    const int tid = threadIdx.x;

    if (blockIdx.x < gb) {
        // ---------------- gemm1 body ----------------
        for (int i = tid; i < WPW / 8; i += 256)
            ((uint4*)wlds)[i] = ((const uint4*)Wp)[i];
        __syncthreads();
        const int wid = tid >> 6;
        const int l   = tid & 63;
        const int lr  = l & 15;
        const int lg  = l >> 4;
#pragma unroll
        for (int rt = 0; rt < 4; ++rt) {
            const int row0 = blockIdx.x * 256 + rt * 64 + wid * 16;
            const int arow = row0 + lr;
            const bool rowok = arow < n;
            const float* xr = X + (size_t)arow * 128;
            bf16x8 ahi[4], alo[4];
#pragma unroll
            for (int kt = 0; kt < 4; ++kt) {
                float v[8];
                if (rowok) {
                    float4 p0 = *(const float4*)(xr + 32 * kt + 8 * lg);
                    float4 p1 = *(const float4*)(xr + 32 * kt + 8 * lg + 4);
                    v[0] = p0.x; v[1] = p0.y; v[2] = p0.z; v[3] = p0.w;
                    v[4] = p1.x; v[5] = p1.y; v[6] = p1.z; v[7] = p1.w;
                } else {
#pragma unroll
                    for (int r = 0; r < 8; ++r) v[r] = 0.f;
                }
#pragma unroll
                for (int r = 0; r < 8; ++r) {
                    u16 hi = f2bf(v[r]);
                    ahi[kt][r] = (short)hi;
                    alo[kt][r] = (short)f2bf(v[r] - bf2f(hi));
                }
            }
#pragma unroll
            for (int ct = 0; ct < NCT; ++ct) {
                f32x4 acc = {0.f, 0.f, 0.f, 0.f};
                const u16* whi = wlds + (size_t)(ct * 4) * 512 + l * 8;
                const u16* wlo = whi + (size_t)NCT * 4 * 512;
#pragma unroll
                for (int kt = 0; kt < 4; ++kt) {
                    bf16x8 bh = *(const bf16x8*)(whi + kt * 512);
                    bf16x8 bl = *(const bf16x8*)(wlo + kt * 512);
                    acc = __builtin_amdgcn_mfma_f32_16x16x32_bf16(ahi[kt], bh, acc, 0, 0, 0);
                    acc = __builtin_amdgcn_mfma_f32_16x16x32_bf16(alo[kt], bh, acc, 0, 0, 0);
                    acc = __builtin_amdgcn_mfma_f32_16x16x32_bf16(ahi[kt], bl, acc, 0, 0, 0);
                }
#pragma unroll
                for (int r = 0; r < 4; ++r) {
                    int row = row0 + lg * 4 + r;
                    if (row < n) Y[(size_t)row * 128 + 16 * ct + lr] = f2bf(acc[r]);
                }
            }
        }
    } else {
        // ---------------- binA body (int4-vectorized) ----------------
        const int b = blockIdx.x - gb;
        const int EN = E + n;
        const int t0 = b * EPB;
        const int t1 = min(t0 + EPB, EN);
        hist[tid] = 0;
        __syncthreads();
        // pass 1: histogram of destination buckets (4 edges/lane/iter)
        for (int t = t0 + tid * 4; t < t1; t += 1024) {
            if (t + 4 <= t1 && t + 4 <= E) {
                int4 d4 = *(const int4*)(ei + E + t);
                atomicAdd(&hist[d4.x >> 8], 1);
                atomicAdd(&hist[d4.y >> 8], 1);
                atomicAdd(&hist[d4.z >> 8], 1);
                atomicAdd(&hist[d4.w >> 8], 1);
            } else {
#pragma unroll
                for (int j = 0; j < 4; ++j) {
                    int tt = t + j;
                    if (tt >= t1) break;
                    int d = (tt < E) ? ei[E + tt] : (tt - E);
                    atomicAdd(&hist[d >> 8], 1);
                }
            }
        }
        __syncthreads();
        // reserve: one global atomic per (block,bucket); hist becomes global cursor
        if (tid < nbuk) {
            int r = hist[tid];
            int g = (r > 0) ? atomicAdd(&bcur[tid], r) : 0;
            hist[tid] = tid * CAP + g;
        }
        __syncthreads();
        // pass 2: place records via LDS cursors (4 edges/lane/iter)
        for (int t = t0 + tid * 4; t < t1; t += 1024) {
            if (t + 4 <= t1 && t + 4 <= E) {
                int4 s4 = *(const int4*)(ei + t);
                int4 d4 = *(const int4*)(ei + E + t);
                int p0 = atomicAdd(&hist[d4.x >> 8], 1);
                int p1 = atomicAdd(&hist[d4.y >> 8], 1);
                int p2 = atomicAdd(&hist[d4.z >> 8], 1);
                int p3 = atomicAdd(&hist[d4.w >> 8], 1);
                if (p0 < ((d4.x >> 8) + 1) * CAP) tmp[p0] = (u32)s4.x | ((u32)(d4.x & 255) << 16);
                if (p1 < ((d4.y >> 8) + 1) * CAP) tmp[p1] = (u32)s4.y | ((u32)(d4.y & 255) << 16);
                if (p2 < ((d4.z >> 8) + 1) * CAP) tmp[p2] = (u32)s4.z | ((u32)(d4.z & 255) << 16);
                if (p3 < ((d4.w >> 8) + 1) * CAP) tmp[p3] = (u32)s4.w | ((u32)(d4.w & 255) << 16);
            } else {
#pragma unroll
                for (int j = 0; j < 4; ++j) {
                    int tt = t + j;
                    if (tt >= t1) break;
                    int s, d;
                    if (tt < E) { s = ei[tt]; d = ei[E + tt]; }
                    else        { s = tt - E; d = s; }
                    int bk = d >> 8;
                    int pos = atomicAdd(&hist[bk], 1);
                    if (pos < (bk + 1) * CAP)
                        tmp[pos] = (u32)s | ((u32)(d & 255) << 16);
                }
            }
        }
    }
}

// binB1: per bucket — inline bucket-base scan (over bcur), LDS degree count +
// scan -> row_ptr, dis. Last bucket writes row_ptr[n]. No global atomics.
__global__ __launch_bounds__(256) void k_binB1(const u32* __restrict__ tmp,
                                               const int* __restrict__ bcur,
                                               int* __restrict__ row_ptr,
                                               float* __restrict__ dis,
                                               int n, int nbuk) {
    __shared__ int sdat[256];
    __shared__ int cnt_l[256];
    __shared__ int s_gbase;
    const int b = blockIdx.x;
    const int tid = threadIdx.x;
    int v = (tid < nbuk) ? min(bcur[tid], CAP) : 0;
    int ex0 = block_scan_excl(v, sdat);
    if (tid == b) s_gbase = ex0;
    if (b == nbuk - 1 && tid == 0) row_ptr[n] = sdat[255];
    __syncthreads();
    const int gbase = s_gbase;
    const int total = min(bcur[b], CAP);
    const u32* rec0 = tmp + (size_t)b * CAP;
    cnt_l[tid] = 0;
    __syncthreads();
    for (int i = tid; i < total; i += 256)
        atomicAdd(&cnt_l[rec0[i] >> 16], 1);
    __syncthreads();
    int deg = cnt_l[tid];
    int ex = block_scan_excl(deg, sdat);
    int node = b * 256 + tid;
    if (node < n) {
        row_ptr[node] = gbase + ex;
        dis[node] = rsqrtf((float)deg);
    }
}

// binB2: per bucket — cursors seeded straight from row_ptr (no recount); place
// es32 records {src16 | bf16(dis[src]*dis[dst])<<16} via LDS cursors; copy out.
__global__ __launch_bounds__(256) void k_binB2(const u32* __restrict__ tmp,
                                               const int* __restrict__ bcur,
                                               const int* __restrict__ row_ptr,
                                               const float* __restrict__ dis,
                                               u32* __restrict__ es, int n) {
    __shared__ int lcur[256];
    __shared__ float ldis[256];
    __shared__ u32 es_lds[CAP];
    const int b = blockIdx.x;
    const int tid = threadIdx.x;
    const int total = min(bcur[b], CAP);
    const int node0 = b * 256;
    const int gbase = row_ptr[node0];
    int node = node0 + tid;
    lcur[tid] = (node < n) ? (row_ptr[node] - gbase) : 0;
    ldis[tid] = (node < n) ? dis[node] : 0.f;
    __syncthreads();
    const u32* rec0 = tmp + (size_t)b * CAP;
    for (int i = tid; i < total; i += 256) {
        u32 rec = rec0[i];
        int dl = rec >> 16;
        int s  = rec & 0xffff;
        float nrm = dis[s] * ldis[dl];
        int p = atomicAdd(&lcur[dl], 1);
        es_lds[p] = (u32)s | ((u32)f2bf(nrm) << 16);
    }
    __syncthreads();
    for (int i = tid; i < total; i += 256)
        es[gbase + i] = es_lds[i];
}

// ------- GEMM2: h2[n,64](bf16) = a1[n,128](bf16) @ W2, 2-term (A exact bf16) --------

__global__ __launch_bounds__(256) void k_gemm2(const u16* __restrict__ A,
                                               const u16* __restrict__ Wp,
                                               u16* __restrict__ Y, int n) {
    constexpr int NCT = 4;
    constexpr int WPW = 2 * NCT * 4 * 64 * 8;
    __shared__ u16 wlds[WPW];
    for (int i = threadIdx.x; i < WPW / 8; i += 256)
        ((uint4*)wlds)[i] = ((const uint4*)Wp)[i];
    __syncthreads();
    const int wid = threadIdx.x >> 6;
    const int l   = threadIdx.x & 63;
    const int lr  = l & 15;
    const int lg  = l >> 4;
#pragma unroll
    for (int rt = 0; rt < 4; ++rt) {
        const int row0 = blockIdx.x * 256 + rt * 64 + wid * 16;
        const int arow = row0 + lr;
        const bool rowok = arow < n;
        bf16x8 a[4];
#pragma unroll
        for (int kt = 0; kt < 4; ++kt) {
            if (rowok) {
                a[kt] = *(const bf16x8*)(A + (size_t)arow * 128 + 32 * kt + 8 * lg);
            } else {
#pragma unroll
                for (int r = 0; r < 8; ++r) a[kt][r] = 0;
            }
        }
#pragma unroll
        for (int ct = 0; ct < NCT; ++ct) {
            f32x4 acc = {0.f, 0.f, 0.f, 0.f};
            const u16* whi = wlds + (size_t)(ct * 4) * 512 + l * 8;
            const u16* wlo = whi + (size_t)NCT * 4 * 512;
#pragma unroll
            for (int kt = 0; kt < 4; ++kt) {
                bf16x8 bh = *(const bf16x8*)(whi + kt * 512);
                bf16x8 bl = *(const bf16x8*)(wlo + kt * 512);
                acc = __builtin_amdgcn_mfma_f32_16x16x32_bf16(a[kt], bh, acc, 0, 0, 0);
                acc = __builtin_amdgcn_mfma_f32_16x16x32_bf16(a[kt], bl, acc, 0, 0, 0);
            }
#pragma unroll
            for (int r = 0; r < 4; ++r) {
                int row = row0 + lg * 4 + r;
                if (row < n) Y[(size_t)row * 64 + 16 * ct + lr] = f2bf(acc[r]);
            }
        }
    }
}

// ------- agg128: 2 half-wave edge streams x 8-unroll (16 edges in flight) ----------
// record r: src = r&0xffff, w = bf16(dis[s]*dis[d]) in high 16 bits.

__global__ __launch_bounds__(256) void k_agg128(const u16* __restrict__ h,
                                                const int* __restrict__ row_ptr,
                                                const u32* __restrict__ es,
                                                const float* __restrict__ bias,
                                                u16* __restrict__ out, int n) {
    int node = blockIdx.x * 4 + (threadIdx.x >> 6);
    if (node >= n) return;
    int lane = threadIdx.x & 63;
    int half = lane >> 5;
    int li   = lane & 31;      // cols 4li..4li+3
    int beg = row_ptr[node], end = row_ptr[node + 1];
    const u16* hp = h + li * 4;
    float a0 = 0.f, a1 = 0.f, a2 = 0.f, a3 = 0.f;
    float b0 = 0.f, b1 = 0.f, b2 = 0.f, b3 = 0.f;
    float c0 = 0.f, c1 = 0.f, c2 = 0.f, c3 = 0.f;
    float d0 = 0.f, d1 = 0.f, d2 = 0.f, d3 = 0.f;
    int e = beg + half;
    for (; e + 14 < end; e += 16) {
        u32 r0 = es[e],      r1 = es[e + 2],  r2 = es[e + 4],  r3 = es[e + 6];
        u32 r4 = es[e + 8],  r5 = es[e + 10], r6 = es[e + 12], r7 = es[e + 14];
        ushort4 v0 = *(const ushort4*)(hp + (size_t)(r0 & 0xffff) * 128);
        ushort4 v1 = *(const ushort4*)(hp + (size_t)(r1 & 0xffff) * 128);
        ushort4 v2 = *(const ushort4*)(hp + (size_t)(r2 & 0xffff) * 128);
        ushort4 v3 = *(const ushort4*)(hp + (size_t)(r3 & 0xffff) * 128);
        ushort4 v4 = *(const ushort4*)(hp + (size_t)(r4 & 0xffff) * 128);
        ushort4 v5 = *(const ushort4*)(hp + (size_t)(r5 & 0xffff) * 128);
        ushort4 v6 = *(const ushort4*)(hp + (size_t)(r6 & 0xffff) * 128);
        ushort4 v7 = *(const ushort4*)(hp + (size_t)(r7 & 0xffff) * 128);
        float w0 = bf2f((u16)(r0 >> 16)), w1 = bf2f((u16)(r1 >> 16));
        float w2 = bf2f((u16)(r2 >> 16)), w3 = bf2f((u16)(r3 >> 16));
        float w4 = bf2f((u16)(r4 >> 16)), w5 = bf2f((u16)(r5 >> 16));
        float w6 = bf2f((u16)(r6 >> 16)), w7 = bf2f((u16)(r7 >> 16));
        a0 += w0 * bf2f(v0.x); a1 += w0 * bf2f(v0.y);
        a2 += w0 * bf2f(v0.z); a3 += w0 * bf2f(v0.w);
        b0 += w1 * bf2f(v1.x); b1 += w1 * bf2f(v1.y);
        b2 += w1 * bf2f(v1.z); b3 += w1 * bf2f(v1.w);
        c0 += w2 * bf2f(v2.x); c1 += w2 * bf2f(v2.y);
        c2 += w2 * bf2f(v2.z); c3 += w2 * bf2f(v2.w);
        d0 += w3 * bf2f(v3.x); d1 += w3 * bf2f(v3.y);
        d2 += w3 * bf2f(v3.z); d3 += w3 * bf2f(v3.w);
        a0 += w4 * bf2f(v4.x); a1 += w4 * bf2f(v4.y);
        a2 += w4 * bf2f(v4.z); a3 += w4 * bf2f(v4.w);
        b0 += w5 * bf2f(v5.x); b1 += w5 * bf2f(v5.y);
        b2 += w5 * bf2f(v5.z); b3 += w5 * bf2f(v5.w);
        c0 += w6 * bf2f(v6.x); c1 += w6 * bf2f(v6.y);
        c2 += w6 * bf2f(v6.z); c3 += w6 * bf2f(v6.w);
        d0 += w7 * bf2f(v7.x); d1 += w7 * bf2f(v7.y);
        d2 += w7 * bf2f(v7.z); d3 += w7 * bf2f(v7.w);
    }
    for (; e < end; e += 2) {
        u32 r0 = es[e];
        float w0 = bf2f((u16)(r0 >> 16));
        ushort4 v0 = *(const ushort4*)(hp + (size_t)(r0 & 0xffff) * 128);
        a0 += w0 * bf2f(v0.x); a1 += w0 * bf2f(v0.y);
        a2 += w0 * bf2f(v0.z); a3 += w0 * bf2f(v0.w);
    }
    a0 = (a0 + b0) + (c0 + d0);
    a1 = (a1 + b1) + (c1 + d1);
    a2 = (a2 + b2) + (c2 + d2);
    a3 = (a3 + b3) + (c3 + d3);
    a0 += __shfl_xor(a0, 32, 64);
    a1 += __shfl_xor(a1, 32, 64);
    a2 += __shfl_xor(a2, 32, 64);
    a3 += __shfl_xor(a3, 32, 64);
    if (half == 0) {
        float4 bv = *(const float4*)(bias + 4 * li);
        a0 = fmaxf(a0 + bv.x, 0.f);
        a1 = fmaxf(a1 + bv.y, 0.f);
        a2 = fmaxf(a2 + bv.z, 0.f);
        a3 = fmaxf(a3 + bv.w, 0.f);
        ushort4 o;
        o.x = f2bf(a0); o.y = f2bf(a1); o.z = f2bf(a2); o.w = f2bf(a3);
        *(ushort4*)(out + (size_t)node * 128 + 4 * li) = o;
    }
}

// ------- agg64: 4 quarter-wave edge streams x 4-unroll (16 edges in flight) --------

__global__ __launch_bounds__(256) void k_agg64(const u16* __restrict__ h,
                                               const int* __restrict__ row_ptr,
                                               const u32* __restrict__ es,
                                               const float* __restrict__ bias,
                                               float* __restrict__ out, int n) {
    int node = blockIdx.x * 4 + (threadIdx.x >> 6);
    if (node >= n) return;
    int lane = threadIdx.x & 63;
    int q  = lane >> 4;
    int li = lane & 15;        // cols 4li..4li+3
    int beg = row_ptr[node], end = row_ptr[node + 1];
    const u16* hp = h + li * 4;
    float a0 = 0.f, a1 = 0.f, a2 = 0.f, a3 = 0.f;
    float b0 = 0.f, b1 = 0.f, b2 = 0.f, b3 = 0.f;
    float c0 = 0.f, c1 = 0.f, c2 = 0.f, c3 = 0.f;
    float d0 = 0.f, d1 = 0.f, d2 = 0.f, d3 = 0.f;
    int e = beg + q;
    for (; e + 12 < end; e += 16) {
        u32 r0 = es[e], r1 = es[e + 4], r2 = es[e + 8], r3 = es[e + 12];
        ushort4 v0 = *(const ushort4*)(hp + (size_t)(r0 & 0xffff) * 64);
        ushort4 v1 = *(const ushort4*)(hp + (size_t)(r1 & 0xffff) * 64);
        ushort4 v2 = *(const ushort4*)(hp + (size_t)(r2 & 0xffff) * 64);
        ushort4 v3 = *(const ushort4*)(hp + (size_t)(r3 & 0xffff) * 64);
        float w0 = bf2f((u16)(r0 >> 16)), w1 = bf2f((u16)(r1 >> 16));
        float w2 = bf2f((u16)(r2 >> 16)), w3 = bf2f((u16)(r3 >> 16));
        a0 += w0 * bf2f(v0.x); a1 += w0 * bf2f(v0.y);
        a2 += w0 * bf2f(v0.z); a3 += w0 * bf2f(v0.w);
        b0 += w1 * bf2f(v1.x); b1 += w1 * bf2f(v1.y);
        b2 += w1 * bf2f(v1.z); b3 += w1 * bf2f(v1.w);
        c0 += w2 * bf2f(v2.x); c1 += w2 * bf2f(v2.y);
        c2 += w2 * bf2f(v2.z); c3 += w2 * bf2f(v2.w);
        d0 += w3 * bf2f(v3.x); d1 += w3 * bf2f(v3.y);
        d2 += w3 * bf2f(v3.z); d3 += w3 * bf2f(v3.w);
    }
    for (; e < end; e += 4) {
        u32 r0 = es[e];
        float w0 = bf2f((u16)(r0 >> 16));
        ushort4 v0 = *(const ushort4*)(hp + (size_t)(r0 & 0xffff) * 64);
        a0 += w0 * bf2f(v0.x); a1 += w0 * bf2f(v0.y);
        a2 += w0 * bf2f(v0.z); a3 += w0 * bf2f(v0.w);
    }
    a0 = (a0 + b0) + (c0 + d0);
    a1 = (a1 + b1) + (c1 + d1);
    a2 = (a2 + b2) + (c2 + d2);
    a3 = (a3 + b3) + (c3 + d3);
    a0 += __shfl_xor(a0, 16, 64); a0 += __shfl_xor(a0, 32, 64);
    a1 += __shfl_xor(a1, 16, 64); a1 += __shfl_xor(a1, 32, 64);
    a2 += __shfl_xor(a2, 16, 64); a2 += __shfl_xor(a2, 32, 64);
    a3 += __shfl_xor(a3, 16, 64); a3 += __shfl_xor(a3, 32, 64);
    if (q == 0) {
        float4 bv = *(const float4*)(bias + 4 * li);
        float4 o;
        o.x = a0 + bv.x; o.y = a1 + bv.y; o.z = a2 + bv.z; o.w = a3 + bv.w;
        *(float4*)(out + (size_t)node * 64 + 4 * li) = o;
    }
}

// ---------------- launch ----------------

static inline char* alignp(char* p, size_t a) {
    return (char*)(((uintptr_t)p + a - 1) & ~(uintptr_t)(a - 1));
}

extern "C" void kernel_launch(void* const* d_in, const int* in_sizes, int n_in,
                              void* d_out, int out_size, void* d_ws, size_t ws_size,
                              hipStream_t stream) {
    const float* x  = (const float*)d_in[0];
    const int*   ei = (const int*)d_in[1];
    const float* W1 = (const float*)d_in[2];
    const float* b1 = (const float*)d_in[3];
    const float* W2 = (const float*)d_in[4];
    const float* b2 = (const float*)d_in[5];
    float* out = (float*)d_out;

    const int n     = in_sizes[0] / IN_F;
    const int E     = in_sizes[1] / 2;
    const int EN    = E + n;
    const int NBUK  = (n + 255) / 256;
    const int GB    = (n + 255) / 256;
    const int NBLKA = (EN + EPB - 1) / EPB;

    char* w = (char*)d_ws;
    int*   row_ptr  = (int*)w;   w = alignp(w + (size_t)(n + 1) * 4, 256);
    int*   bcur     = (int*)w;   w = alignp(w + (size_t)NBUK * 4, 256);
    float* dis      = (float*)w; w = alignp(w + (size_t)n * 4, 256);
    u32*   tmp      = (u32*)w;   w = alignp(w + (size_t)NBUK * CAP * 4, 256);
    u32*   es       = (u32*)w;   w = alignp(w + (size_t)EN * 4, 256);
    u16*   w1p      = (u16*)w;   w = alignp(w + (size_t)2 * 8 * 4 * 64 * 8 * 2, 256);
    u16*   w2p      = (u16*)w;   w = alignp(w + (size_t)2 * 4 * 4 * 64 * 8 * 2, 256);
    u16*   h1b      = (u16*)w;   w = alignp(w + (size_t)n * 128 * 2, 256);
    u16*   a1b      = (u16*)w;   w = alignp(w + (size_t)n * 128 * 2, 256);
    u16*   h2b      = h1b;  // reuse: h1b dead after first aggregation

    k_setup<<<16, 256, 0, stream>>>(W1, W2, w1p, w2p, bcur, NBUK);
    k_ag1<<<GB + NBLKA, 256, 0, stream>>>(x, w1p, h1b, ei, bcur, tmp, E, n, NBUK, GB);
    k_binB1<<<NBUK, 256, 0, stream>>>(tmp, bcur, row_ptr, dis, n, NBUK);
    k_binB2<<<NBUK, 256, 0, stream>>>(tmp, bcur, row_ptr, dis, es, n);

    k_agg128<<<(n + 3) / 4, 256, 0, stream>>>(h1b, row_ptr, es, b1, a1b, n);
    k_gemm2<<<GB, 256, 0, stream>>>(a1b, w2p, h2b, n);
    k_agg64<<<(n + 3) / 4, 256, 0, stream>>>(h2b, row_ptr, es, b2, out, n);
}

// Round 18
// 116.814 us; speedup vs baseline: 1.6161x; 1.0838x over previous
//
#include <hip/hip_runtime.h>

typedef unsigned short u16;
typedef unsigned int u32;
typedef __attribute__((ext_vector_type(8))) short bf16x8;
typedef __attribute__((ext_vector_type(4))) float f32x4;

#define IN_F 128
#define CAP  8192   // record capacity per 256-node bucket (mean ~4.4K, +58 sigma)
#define EPB  2048   // edges per binA block (smaller => more blocks => latency hiding)

// ---------- helpers ----------
__device__ inline float bf2f(u16 v) {
    return __uint_as_float(((unsigned)v) << 16);
}
__device__ inline u16 f2bf(float f) {
    unsigned u = __float_as_uint(f);
    return (u16)((u + 0x7fffu + ((u >> 16) & 1u)) >> 16);
}

__device__ inline int block_scan_excl(int v, int* sdat) {
    int tid = threadIdx.x;
    sdat[tid] = v;
    __syncthreads();
#pragma unroll
    for (int off = 1; off < 256; off <<= 1) {
        int t = (tid >= off) ? sdat[tid - off] : 0;
        __syncthreads();
        sdat[tid] += t;
        __syncthreads();
    }
    return sdat[tid] - v;
}

// ---------------- setup: zero bcur + pack W1/W2 into MFMA B-fragment order --------

template<int M>
__device__ inline void packW_body(const float* __restrict__ W, u16* __restrict__ Wp, int t) {
    constexpr int NCT = M / 16;
    int l  = t & 63;
    int q  = t >> 6;
    int kt = q & 3;
    int q2 = q >> 2;
    int ct = q2 % NCT;
    int h  = q2 / NCT;
    int col   = 16 * ct + (l & 15);
    int krow0 = 32 * kt + 8 * (l >> 4);
    u16* outp = Wp + (size_t)t * 8;
#pragma unroll
    for (int r = 0; r < 8; ++r) {
        float w  = W[(size_t)(krow0 + r) * M + col];
        u16 hi   = f2bf(w);
        outp[r] = (h == 0) ? hi : f2bf(w - bf2f(hi));
    }
}

__global__ __launch_bounds__(256) void k_setup(const float* __restrict__ W1,
                                               const float* __restrict__ W2,
                                               u16* __restrict__ w1p,
                                               u16* __restrict__ w2p,
                                               int* bcur, int nbuk) {
    int t = blockIdx.x * 256 + threadIdx.x;
    if (t < nbuk) bcur[t] = 0;
    if (t < 2 * 8 * 4 * 64) packW_body<128>(W1, w1p, t);
    if (t < 2 * 4 * 4 * 64) packW_body<64>(W2, w2p, t);
}

// ---------------- fused: gemm1 (blocks [0,gb)) || binA (blocks [gb, gb+nblkA)) ------

__global__ __launch_bounds__(256) void k_ag1(const float* __restrict__ X,
                                             const u16* __restrict__ Wp,
                                             u16* __restrict__ Y,
                                             const int* __restrict__ ei,
                                             int* bcur, u32* __restrict__ tmp,
                                             int E, int n, int nbuk, int gb) {
    constexpr int NCT = 8;
    constexpr int WPW = 2 * NCT * 4 * 64 * 8;
    __shared__ u16 wlds[WPW];     // 64 KB (gemm1 branch)
    __shared__ int hist[256];     // 1 KB  (binA branch)
    const int tid = threadIdx.x;

    if (blockIdx.x < gb) {
        // ---------------- gemm1 body ----------------
        for (int i = tid; i < WPW / 8; i += 256)
            ((uint4*)wlds)[i] = ((const uint4*)Wp)[i];
        __syncthreads();
        const int wid = tid >> 6;
        const int l   = tid & 63;
        const int lr  = l & 15;
        const int lg  = l >> 4;
#pragma unroll
        for (int rt = 0; rt < 4; ++rt) {
            const int row0 = blockIdx.x * 256 + rt * 64 + wid * 16;
            const int arow = row0 + lr;
            const bool rowok = arow < n;
            const float* xr = X + (size_t)arow * 128;
            bf16x8 ahi[4], alo[4];
#pragma unroll
            for (int kt = 0; kt < 4; ++kt) {
                float v[8];
                if (rowok) {
                    float4 p0 = *(const float4*)(xr + 32 * kt + 8 * lg);
                    float4 p1 = *(const float4*)(xr + 32 * kt + 8 * lg + 4);
                    v[0] = p0.x; v[1] = p0.y; v[2] = p0.z; v[3] = p0.w;
                    v[4] = p1.x; v[5] = p1.y; v[6] = p1.z; v[7] = p1.w;
                } else {
#pragma unroll
                    for (int r = 0; r < 8; ++r) v[r] = 0.f;
                }
#pragma unroll
                for (int r = 0; r < 8; ++r) {
                    u16 hi = f2bf(v[r]);
                    ahi[kt][r] = (short)hi;
                    alo[kt][r] = (short)f2bf(v[r] - bf2f(hi));
                }
            }
#pragma unroll
            for (int ct = 0; ct < NCT; ++ct) {
                f32x4 acc = {0.f, 0.f, 0.f, 0.f};
                const u16* whi = wlds + (size_t)(ct * 4) * 512 + l * 8;
                const u16* wlo = whi + (size_t)NCT * 4 * 512;
#pragma unroll
                for (int kt = 0; kt < 4; ++kt) {
                    bf16x8 bh = *(const bf16x8*)(whi + kt * 512);
                    bf16x8 bl = *(const bf16x8*)(wlo + kt * 512);
                    acc = __builtin_amdgcn_mfma_f32_16x16x32_bf16(ahi[kt], bh, acc, 0, 0, 0);
                    acc = __builtin_amdgcn_mfma_f32_16x16x32_bf16(alo[kt], bh, acc, 0, 0, 0);
                    acc = __builtin_amdgcn_mfma_f32_16x16x32_bf16(ahi[kt], bl, acc, 0, 0, 0);
                }
#pragma unroll
                for (int r = 0; r < 4; ++r) {
                    int row = row0 + lg * 4 + r;
                    if (row < n) Y[(size_t)row * 128 + 16 * ct + lr] = f2bf(acc[r]);
                }
            }
        }
    } else {
        // ---------------- binA body (int4-vectorized) ----------------
        const int b = blockIdx.x - gb;
        const int EN = E + n;
        const int t0 = b * EPB;
        const int t1 = min(t0 + EPB, EN);
        hist[tid] = 0;
        __syncthreads();
        for (int t = t0 + tid * 4; t < t1; t += 1024) {
            if (t + 4 <= t1 && t + 4 <= E) {
                int4 d4 = *(const int4*)(ei + E + t);
                atomicAdd(&hist[d4.x >> 8], 1);
                atomicAdd(&hist[d4.y >> 8], 1);
                atomicAdd(&hist[d4.z >> 8], 1);
                atomicAdd(&hist[d4.w >> 8], 1);
            } else {
#pragma unroll
                for (int j = 0; j < 4; ++j) {
                    int tt = t + j;
                    if (tt >= t1) break;
                    int d = (tt < E) ? ei[E + tt] : (tt - E);
                    atomicAdd(&hist[d >> 8], 1);
                }
            }
        }
        __syncthreads();
        if (tid < nbuk) {
            int r = hist[tid];
            int g = (r > 0) ? atomicAdd(&bcur[tid], r) : 0;
            hist[tid] = tid * CAP + g;
        }
        __syncthreads();
        for (int t = t0 + tid * 4; t < t1; t += 1024) {
            if (t + 4 <= t1 && t + 4 <= E) {
                int4 s4 = *(const int4*)(ei + t);
                int4 d4 = *(const int4*)(ei + E + t);
                int p0 = atomicAdd(&hist[d4.x >> 8], 1);
                int p1 = atomicAdd(&hist[d4.y >> 8], 1);
                int p2 = atomicAdd(&hist[d4.z >> 8], 1);
                int p3 = atomicAdd(&hist[d4.w >> 8], 1);
                if (p0 < ((d4.x >> 8) + 1) * CAP) tmp[p0] = (u32)s4.x | ((u32)(d4.x & 255) << 16);
                if (p1 < ((d4.y >> 8) + 1) * CAP) tmp[p1] = (u32)s4.y | ((u32)(d4.y & 255) << 16);
                if (p2 < ((d4.z >> 8) + 1) * CAP) tmp[p2] = (u32)s4.z | ((u32)(d4.z & 255) << 16);
                if (p3 < ((d4.w >> 8) + 1) * CAP) tmp[p3] = (u32)s4.w | ((u32)(d4.w & 255) << 16);
            } else {
#pragma unroll
                for (int j = 0; j < 4; ++j) {
                    int tt = t + j;
                    if (tt >= t1) break;
                    int s, d;
                    if (tt < E) { s = ei[tt]; d = ei[E + tt]; }
                    else        { s = tt - E; d = s; }
                    int bk = d >> 8;
                    int pos = atomicAdd(&hist[bk], 1);
                    if (pos < (bk + 1) * CAP)
                        tmp[pos] = (u32)s | ((u32)(d & 255) << 16);
                }
            }
        }
    }
}

// binB1: per bucket — inline bucket-base scan, LDS degree count + scan -> row_ptr, dis.
__global__ __launch_bounds__(256) void k_binB1(const u32* __restrict__ tmp,
                                               const int* __restrict__ bcur,
                                               int* __restrict__ row_ptr,
                                               float* __restrict__ dis,
                                               int n, int nbuk) {
    __shared__ int sdat[256];
    __shared__ int cnt_l[256];
    __shared__ int s_gbase;
    const int b = blockIdx.x;
    const int tid = threadIdx.x;
    int v = (tid < nbuk) ? min(bcur[tid], CAP) : 0;
    int ex0 = block_scan_excl(v, sdat);
    if (tid == b) s_gbase = ex0;
    if (b == nbuk - 1 && tid == 0) row_ptr[n] = sdat[255];
    __syncthreads();
    const int gbase = s_gbase;
    const int total = min(bcur[b], CAP);
    const u32* rec0 = tmp + (size_t)b * CAP;
    cnt_l[tid] = 0;
    __syncthreads();
    for (int i = tid; i < total; i += 256)
        atomicAdd(&cnt_l[rec0[i] >> 16], 1);
    __syncthreads();
    int deg = cnt_l[tid];
    int ex = block_scan_excl(deg, sdat);
    int node = b * 256 + tid;
    if (node < n) {
        row_ptr[node] = gbase + ex;
        dis[node] = rsqrtf((float)deg);
    }
}

// binB2: per bucket — cursors seeded from row_ptr; place es32 records
// {src16 | bf16(dis[src]*dis[dst])<<16} via LDS cursors; copy out.
__global__ __launch_bounds__(256) void k_binB2(const u32* __restrict__ tmp,
                                               const int* __restrict__ bcur,
                                               const int* __restrict__ row_ptr,
                                               const float* __restrict__ dis,
                                               u32* __restrict__ es, int n) {
    __shared__ int lcur[256];
    __shared__ float ldis[256];
    __shared__ u32 es_lds[CAP];
    const int b = blockIdx.x;
    const int tid = threadIdx.x;
    const int total = min(bcur[b], CAP);
    const int node0 = b * 256;
    const int gbase = row_ptr[node0];
    int node = node0 + tid;
    lcur[tid] = (node < n) ? (row_ptr[node] - gbase) : 0;
    ldis[tid] = (node < n) ? dis[node] : 0.f;
    __syncthreads();
    const u32* rec0 = tmp + (size_t)b * CAP;
    for (int i = tid; i < total; i += 256) {
        u32 rec = rec0[i];
        int dl = rec >> 16;
        int s  = rec & 0xffff;
        float nrm = dis[s] * ldis[dl];
        int p = atomicAdd(&lcur[dl], 1);
        es_lds[p] = (u32)s | ((u32)f2bf(nrm) << 16);
    }
    __syncthreads();
    for (int i = tid; i < total; i += 256)
        es[gbase + i] = es_lds[i];
}

// ------- GEMM2: h2[n,64](bf16) = a1[n,128](bf16) @ W2, 2-term (A exact bf16) --------

__global__ __launch_bounds__(256) void k_gemm2(const u16* __restrict__ A,
                                               const u16* __restrict__ Wp,
                                               u16* __restrict__ Y, int n) {
    constexpr int NCT = 4;
    constexpr int WPW = 2 * NCT * 4 * 64 * 8;
    __shared__ u16 wlds[WPW];
    for (int i = threadIdx.x; i < WPW / 8; i += 256)
        ((uint4*)wlds)[i] = ((const uint4*)Wp)[i];
    __syncthreads();
    const int wid = threadIdx.x >> 6;
    const int l   = threadIdx.x & 63;
    const int lr  = l & 15;
    const int lg  = l >> 4;
#pragma unroll
    for (int rt = 0; rt < 4; ++rt) {
        const int row0 = blockIdx.x * 256 + rt * 64 + wid * 16;
        const int arow = row0 + lr;
        const bool rowok = arow < n;
        bf16x8 a[4];
#pragma unroll
        for (int kt = 0; kt < 4; ++kt) {
            if (rowok) {
                a[kt] = *(const bf16x8*)(A + (size_t)arow * 128 + 32 * kt + 8 * lg);
            } else {
#pragma unroll
                for (int r = 0; r < 8; ++r) a[kt][r] = 0;
            }
        }
#pragma unroll
        for (int ct = 0; ct < NCT; ++ct) {
            f32x4 acc = {0.f, 0.f, 0.f, 0.f};
            const u16* whi = wlds + (size_t)(ct * 4) * 512 + l * 8;
            const u16* wlo = whi + (size_t)NCT * 4 * 512;
#pragma unroll
            for (int kt = 0; kt < 4; ++kt) {
                bf16x8 bh = *(const bf16x8*)(whi + kt * 512);
                bf16x8 bl = *(const bf16x8*)(wlo + kt * 512);
                acc = __builtin_amdgcn_mfma_f32_16x16x32_bf16(a[kt], bh, acc, 0, 0, 0);
                acc = __builtin_amdgcn_mfma_f32_16x16x32_bf16(a[kt], bl, acc, 0, 0, 0);
            }
#pragma unroll
            for (int r = 0; r < 4; ++r) {
                int row = row0 + lg * 4 + r;
                if (row < n) Y[(size_t)row * 64 + 16 * ct + lr] = f2bf(acc[r]);
            }
        }
    }
}

// ------- agg128: one node per HALF-WAVE (32 lanes x ushort4 = 128 cols), ------------
// 4-deep unroll over the node's own edge list; no cross-lane reduction.
// record r: src = r&0xffff, w = bf16(dis[s]*dis[d]) in high 16 bits.

__global__ __launch_bounds__(256) void k_agg128(const u16* __restrict__ h,
                                                const int* __restrict__ row_ptr,
                                                const u32* __restrict__ es,
                                                const float* __restrict__ bias,
                                                u16* __restrict__ out, int n) {
    int node = blockIdx.x * 8 + (threadIdx.x >> 5);   // 8 half-waves per block
    if (node >= n) return;
    int l31 = threadIdx.x & 31;       // cols 4*l31 .. 4*l31+3
    int beg = row_ptr[node], end = row_ptr[node + 1];
    const u16* hp = h + l31 * 4;
    float a0 = 0.f, a1 = 0.f, a2 = 0.f, a3 = 0.f;
    float b0 = 0.f, b1 = 0.f, b2 = 0.f, b3 = 0.f;
    float c0 = 0.f, c1 = 0.f, c2 = 0.f, c3 = 0.f;
    float d0 = 0.f, d1 = 0.f, d2 = 0.f, d3 = 0.f;
    int e = beg;
    for (; e + 3 < end; e += 4) {
        u32 r0 = es[e], r1 = es[e + 1], r2 = es[e + 2], r3 = es[e + 3];
        ushort4 v0 = *(const ushort4*)(hp + (size_t)(r0 & 0xffff) * 128);
        ushort4 v1 = *(const ushort4*)(hp + (size_t)(r1 & 0xffff) * 128);
        ushort4 v2 = *(const ushort4*)(hp + (size_t)(r2 & 0xffff) * 128);
        ushort4 v3 = *(const ushort4*)(hp + (size_t)(r3 & 0xffff) * 128);
        float w0 = bf2f((u16)(r0 >> 16)), w1 = bf2f((u16)(r1 >> 16));
        float w2 = bf2f((u16)(r2 >> 16)), w3 = bf2f((u16)(r3 >> 16));
        a0 += w0 * bf2f(v0.x); a1 += w0 * bf2f(v0.y);
        a2 += w0 * bf2f(v0.z); a3 += w0 * bf2f(v0.w);
        b0 += w1 * bf2f(v1.x); b1 += w1 * bf2f(v1.y);
        b2 += w1 * bf2f(v1.z); b3 += w1 * bf2f(v1.w);
        c0 += w2 * bf2f(v2.x); c1 += w2 * bf2f(v2.y);
        c2 += w2 * bf2f(v2.z); c3 += w2 * bf2f(v2.w);
        d0 += w3 * bf2f(v3.x); d1 += w3 * bf2f(v3.y);
        d2 += w3 * bf2f(v3.z); d3 += w3 * bf2f(v3.w);
    }
    for (; e < end; ++e) {
        u32 r0 = es[e];
        float w0 = bf2f((u16)(r0 >> 16));
        ushort4 v0 = *(const ushort4*)(hp + (size_t)(r0 & 0xffff) * 128);
        a0 += w0 * bf2f(v0.x); a1 += w0 * bf2f(v0.y);
        a2 += w0 * bf2f(v0.z); a3 += w0 * bf2f(v0.w);
    }
    a0 = (a0 + b0) + (c0 + d0);
    a1 = (a1 + b1) + (c1 + d1);
    a2 = (a2 + b2) + (c2 + d2);
    a3 = (a3 + b3) + (c3 + d3);
    float4 bv = *(const float4*)(bias + 4 * l31);
    a0 = fmaxf(a0 + bv.x, 0.f);
    a1 = fmaxf(a1 + bv.y, 0.f);
    a2 = fmaxf(a2 + bv.z, 0.f);
    a3 = fmaxf(a3 + bv.w, 0.f);
    ushort4 o;
    o.x = f2bf(a0); o.y = f2bf(a1); o.z = f2bf(a2); o.w = f2bf(a3);
    *(ushort4*)(out + (size_t)node * 128 + 4 * l31) = o;
}

// ------- agg64: one node per QUARTER-WAVE (16 lanes x ushort4 = 64 cols), -----------
// 4-deep unroll over the node's own edge list; no cross-lane reduction.

__global__ __launch_bounds__(256) void k_agg64(const u16* __restrict__ h,
                                               const int* __restrict__ row_ptr,
                                               const u32* __restrict__ es,
                                               const float* __restrict__ bias,
                                               float* __restrict__ out, int n) {
    int node = blockIdx.x * 16 + (threadIdx.x >> 4);  // 16 quarter-waves per block
    if (node >= n) return;
    int l16 = threadIdx.x & 15;       // cols 4*l16 .. 4*l16+3
    int beg = row_ptr[node], end = row_ptr[node + 1];
    const u16* hp = h + l16 * 4;
    float a0 = 0.f, a1 = 0.f, a2 = 0.f, a3 = 0.f;
    float b0 = 0.f, b1 = 0.f, b2 = 0.f, b3 = 0.f;
    float c0 = 0.f, c1 = 0.f, c2 = 0.f, c3 = 0.f;
    float d0 = 0.f, d1 = 0.f, d2 = 0.f, d3 = 0.f;
    int e = beg;
    for (; e + 3 < end; e += 4) {
        u32 r0 = es[e], r1 = es[e + 1], r2 = es[e + 2], r3 = es[e + 3];
        ushort4 v0 = *(const ushort4*)(hp + (size_t)(r0 & 0xffff) * 64);
        ushort4 v1 = *(const ushort4*)(hp + (size_t)(r1 & 0xffff) * 64);
        ushort4 v2 = *(const ushort4*)(hp + (size_t)(r2 & 0xffff) * 64);
        ushort4 v3 = *(const ushort4*)(hp + (size_t)(r3 & 0xffff) * 64);
        float w0 = bf2f((u16)(r0 >> 16)), w1 = bf2f((u16)(r1 >> 16));
        float w2 = bf2f((u16)(r2 >> 16)), w3 = bf2f((u16)(r3 >> 16));
        a0 += w0 * bf2f(v0.x); a1 += w0 * bf2f(v0.y);
        a2 += w0 * bf2f(v0.z); a3 += w0 * bf2f(v0.w);
        b0 += w1 * bf2f(v1.x); b1 += w1 * bf2f(v1.y);
        b2 += w1 * bf2f(v1.z); b3 += w1 * bf2f(v1.w);
        c0 += w2 * bf2f(v2.x); c1 += w2 * bf2f(v2.y);
        c2 += w2 * bf2f(v2.z); c3 += w2 * bf2f(v2.w);
        d0 += w3 * bf2f(v3.x); d1 += w3 * bf2f(v3.y);
        d2 += w3 * bf2f(v3.z); d3 += w3 * bf2f(v3.w);
    }
    for (; e < end; ++e) {
        u32 r0 = es[e];
        float w0 = bf2f((u16)(r0 >> 16));
        ushort4 v0 = *(const ushort4*)(hp + (size_t)(r0 & 0xffff) * 64);
        a0 += w0 * bf2f(v0.x); a1 += w0 * bf2f(v0.y);
        a2 += w0 * bf2f(v0.z); a3 += w0 * bf2f(v0.w);
    }
    a0 = (a0 + b0) + (c0 + d0);
    a1 = (a1 + b1) + (c1 + d1);
    a2 = (a2 + b2) + (c2 + d2);
    a3 = (a3 + b3) + (c3 + d3);
    float4 bv = *(const float4*)(bias + 4 * l16);
    float4 o;
    o.x = a0 + bv.x; o.y = a1 + bv.y; o.z = a2 + bv.z; o.w = a3 + bv.w;
    *(float4*)(out + (size_t)node * 64 + 4 * l16) = o;
}

// ---------------- launch ----------------

static inline char* alignp(char* p, size_t a) {
    return (char*)(((uintptr_t)p + a - 1) & ~(uintptr_t)(a - 1));
}

extern "C" void kernel_launch(void* const* d_in, const int* in_sizes, int n_in,
                              void* d_out, int out_size, void* d_ws, size_t ws_size,
                              hipStream_t stream) {
    const float* x  = (const float*)d_in[0];
    const int*   ei = (const int*)d_in[1];
    const float* W1 = (const float*)d_in[2];
    const float* b1 = (const float*)d_in[3];
    const float* W2 = (const float*)d_in[4];
    const float* b2 = (const float*)d_in[5];
    float* out = (float*)d_out;

    const int n     = in_sizes[0] / IN_F;
    const int E     = in_sizes[1] / 2;
    const int EN    = E + n;
    const int NBUK  = (n + 255) / 256;
    const int GB    = (n + 255) / 256;
    const int NBLKA = (EN + EPB - 1) / EPB;

    char* w = (char*)d_ws;
    int*   row_ptr  = (int*)w;   w = alignp(w + (size_t)(n + 1) * 4, 256);
    int*   bcur     = (int*)w;   w = alignp(w + (size_t)NBUK * 4, 256);
    float* dis      = (float*)w; w = alignp(w + (size_t)n * 4, 256);
    u32*   tmp      = (u32*)w;   w = alignp(w + (size_t)NBUK * CAP * 4, 256);
    u32*   es       = (u32*)w;   w = alignp(w + (size_t)EN * 4, 256);
    u16*   w1p      = (u16*)w;   w = alignp(w + (size_t)2 * 8 * 4 * 64 * 8 * 2, 256);
    u16*   w2p      = (u16*)w;   w = alignp(w + (size_t)2 * 4 * 4 * 64 * 8 * 2, 256);
    u16*   h1b      = (u16*)w;   w = alignp(w + (size_t)n * 128 * 2, 256);
    u16*   a1b      = (u16*)w;   w = alignp(w + (size_t)n * 128 * 2, 256);
    u16*   h2b      = h1b;  // reuse: h1b dead after first aggregation

    k_setup<<<16, 256, 0, stream>>>(W1, W2, w1p, w2p, bcur, NBUK);
    k_ag1<<<GB + NBLKA, 256, 0, stream>>>(x, w1p, h1b, ei, bcur, tmp, E, n, NBUK, GB);
    k_binB1<<<NBUK, 256, 0, stream>>>(tmp, bcur, row_ptr, dis, n, NBUK);
    k_binB2<<<NBUK, 256, 0, stream>>>(tmp, bcur, row_ptr, dis, es, n);

    k_agg128<<<(n + 7) / 8, 256, 0, stream>>>(h1b, row_ptr, es, b1, a1b, n);
    k_gemm2<<<GB, 256, 0, stream>>>(a1b, w2p, h2b, n);
    k_agg64<<<(n + 15) / 16, 256, 0, stream>>>(h2b, row_ptr, es, b2, out, n);
}